// Round 1
// baseline (5955.893 us; speedup 1.0000x reference)
//
#include <hip/hip_runtime.h>
#include <hip/hip_bf16.h>

// XLNet content-stream relative-attention layer + FFN, fp32 correctness-first.
// Sizes (fixed): QLEN=1024 MLEN=1024 BSZ=2 D_MODEL=1024 N_HEAD=16 D_HEAD=64
// D_INNER=4096 KLEN=2048 RLEN=3072. SCALE = 0.125.
//
// rel_shift identity: bd_shifted[i,j] = bd_raw[i, QLEN - i + j]  (verified
// against the reshape/slice definition), so bd is computed directly against
// k_r rows (QLEN - i + j) without materializing the pre-shift tensor.

#define QLEN 1024
#define MLEN 1024
#define BSZ 2
#define DM 1024
#define NH 16
#define DH 64
#define DI 4096
#define KLEN 2048
#define RLEN 3072

// ---------------- block reduction helpers (wave=64, 4 waves/block) ----------
template<bool ISMAX>
__device__ __forceinline__ float block_reduce(float v, float* red, int t) {
    #pragma unroll
    for (int off = 32; off > 0; off >>= 1) {
        float o = __shfl_down(v, off);
        v = ISMAX ? fmaxf(v, o) : (v + o);
    }
    if ((t & 63) == 0) red[t >> 6] = v;
    __syncthreads();
    if (t == 0) {
        float s = red[0];
        #pragma unroll
        for (int w = 1; w < 4; ++w) s = ISMAX ? fmaxf(s, red[w]) : (s + red[w]);
        red[4] = s;
    }
    __syncthreads();
    return red[4];
}

// ---------------- generic fp32 tiled GEMM ----------------------------------
// C[M,N] = A[M,K] @ B  (+bias, +gelu per EPI)
// AMODE 0: A0 row-major [M,K].  AMODE 1: cat(mems,h): row g -> j=g>>1,b=g&1,
//          j<MLEN ? mems[(j*2+b)*K] : h[((j-MLEN)*2+b)*K].
// BT false: B[k*N+n];  BT true: B[n*K+k] (i.e. C = A @ B^T with B [N,K]).
// EPI: 0 none, 1 bias+gelu(tanh approx), 2 bias only.
template<int AMODE, bool BT, int EPI>
__global__ __launch_bounds__(256) void gemm_k(
    const float* __restrict__ A0, const float* __restrict__ A1,
    const float* __restrict__ B, const float* __restrict__ bias,
    float* __restrict__ C, int M, int N, int K)
{
    __shared__ float As[16][65];
    __shared__ float Bs[16][65];
    const int tid = threadIdx.x;
    const int tx = tid & 15, ty = tid >> 4;
    const int rowBase = blockIdx.y * 64;
    const int colBase = blockIdx.x * 64;
    float acc[4][4] = {};

    for (int k0 = 0; k0 < K; k0 += 16) {
        #pragma unroll
        for (int u = 0; u < 4; ++u) {
            int idx = tid + 256 * u;
            int ar = idx >> 4;        // 0..63 tile row
            int ak = idx & 15;        // 0..15 tile k
            int grow = rowBase + ar;
            const float* arow;
            if (AMODE == 0) {
                arow = A0 + (size_t)grow * K;
            } else {
                int j = grow >> 1, b = grow & 1;
                arow = (j < MLEN) ? (A0 + (size_t)(j * 2 + b) * K)
                                  : (A1 + (size_t)((j - MLEN) * 2 + b) * K);
            }
            As[ak][ar] = arow[k0 + ak];
        }
        #pragma unroll
        for (int u = 0; u < 4; ++u) {
            int idx = tid + 256 * u;
            if (!BT) {
                int bk = idx >> 6, bn = idx & 63;
                Bs[bk][bn] = B[(size_t)(k0 + bk) * N + colBase + bn];
            } else {
                int bn = idx >> 4, bk = idx & 15;
                Bs[bk][bn] = B[(size_t)(colBase + bn) * K + k0 + bk];
            }
        }
        __syncthreads();
        #pragma unroll
        for (int kk = 0; kk < 16; ++kk) {
            float a0[4], b0[4];
            #pragma unroll
            for (int u = 0; u < 4; ++u) a0[u] = As[kk][ty * 4 + u];
            #pragma unroll
            for (int u = 0; u < 4; ++u) b0[u] = Bs[kk][tx * 4 + u];
            #pragma unroll
            for (int x = 0; x < 4; ++x)
                #pragma unroll
                for (int y = 0; y < 4; ++y)
                    acc[x][y] = fmaf(a0[x], b0[y], acc[x][y]);
        }
        __syncthreads();
    }

    #pragma unroll
    for (int x = 0; x < 4; ++x) {
        int rr = rowBase + ty * 4 + x;
        #pragma unroll
        for (int y = 0; y < 4; ++y) {
            int cc = colBase + tx * 4 + y;
            float v = acc[x][y];
            if (EPI >= 1) v += bias[cc];
            if (EPI == 1) {
                float targ = 0.7978845608028654f * (v + 0.044715f * v * v * v);
                v = 0.5f * v * (1.0f + tanhf(targ));
            }
            C[(size_t)rr * N + cc] = v;
        }
    }
}

// ---------------- fused per-row relative attention --------------------------
// grid (QLEN, BSZ*NH), 256 threads. One block = one (query row i, batch b, head n).
// score[j] = (qw.k[j] + qr.k_r[QLEN-i+j] + seg blend) * 0.125 - 1e30*(j > i+MLEN)
// softmax over j, then attn_vec[i] = sum_j p[j] v[j].
__global__ __launch_bounds__(256) void attn_k(
    const float* __restrict__ q_h, const float* __restrict__ k_h,
    const float* __restrict__ v_h, const float* __restrict__ k_r,
    const float* __restrict__ seg_mat,
    const float* __restrict__ rwb, const float* __restrict__ rrb,
    const float* __restrict__ rsb, const float* __restrict__ seg_embed,
    float* __restrict__ attn_vec)
{
    __shared__ float qw[DH], qr[DH], qs[DH];
    __shared__ float sc[KLEN];
    __shared__ float red[5];
    __shared__ float efs[2];
    __shared__ float pv[4][DH];

    const int i = blockIdx.x;
    const int bn = blockIdx.y;
    const int b = bn >> 4, n = bn & 15;
    const int t = threadIdx.x;

    if (t < DH) {
        float qv = q_h[(size_t)(i * 2 + b) * DM + n * DH + t];
        qw[t] = qv + rwb[n * DH + t];
        qr[t] = qv + rrb[n * DH + t];
        qs[t] = qv + rsb[n * DH + t];
    }
    __syncthreads();
    if (t < 2) {
        float e = 0.f;
        const float* se = seg_embed + (t * NH + n) * DH;
        for (int d = 0; d < DH; ++d) e += qs[d] * se[d];
        efs[t] = e;
    }
    __syncthreads();
    const float ef0 = efs[0], ef1 = efs[1];

    float myv[8];
    float mymax = -3.0e38f;
    #pragma unroll
    for (int u = 0; u < 8; ++u) {
        int j = t + 256 * u;
        const float4* krow = reinterpret_cast<const float4*>(
            k_h + (size_t)(j * 2 + b) * DM + n * DH);
        const float4* rrow = reinterpret_cast<const float4*>(
            k_r + (size_t)((QLEN - i + j) * 2 + b) * DM + n * DH);
        float ac = 0.f, bd = 0.f;
        #pragma unroll 4
        for (int d4 = 0; d4 < DH / 4; ++d4) {
            float4 kv = krow[d4];
            float4 rv = rrow[d4];
            const float4 qwv = *reinterpret_cast<const float4*>(&qw[d4 * 4]);
            const float4 qrv = *reinterpret_cast<const float4*>(&qr[d4 * 4]);
            ac = fmaf(qwv.x, kv.x, ac); ac = fmaf(qwv.y, kv.y, ac);
            ac = fmaf(qwv.z, kv.z, ac); ac = fmaf(qwv.w, kv.w, ac);
            bd = fmaf(qrv.x, rv.x, bd); bd = fmaf(qrv.y, rv.y, bd);
            bd = fmaf(qrv.z, rv.z, bd); bd = fmaf(qrv.w, rv.w, bd);
        }
        const float* sm = seg_mat + ((size_t)(i * KLEN + j) * 2 + b) * 2;
        float s = (ac + bd + sm[0] * ef0 + sm[1] * ef1) * 0.125f;
        if (j > i + MLEN) s -= 1e30f;
        myv[u] = s;
        mymax = fmaxf(mymax, s);
    }

    float mx = block_reduce<true>(mymax, red, t);
    float mysum = 0.f;
    #pragma unroll
    for (int u = 0; u < 8; ++u) {
        float p = __expf(myv[u] - mx);
        myv[u] = p;
        mysum += p;
    }
    float tot = block_reduce<false>(mysum, red, t);
    float inv = 1.0f / tot;
    #pragma unroll
    for (int u = 0; u < 8; ++u) sc[t + 256 * u] = myv[u] * inv;
    __syncthreads();

    // PV: thread (c = t>>6, d = t&63) sums 512 j's.
    const int d = t & 63, c = t >> 6;
    float acc = 0.f;
    for (int j = c * 512; j < c * 512 + 512; ++j)
        acc = fmaf(sc[j], v_h[(size_t)(j * 2 + b) * DM + n * DH + d], acc);
    pv[c][d] = acc;
    __syncthreads();
    if (t < DH) {
        float s = pv[0][t] + pv[1][t] + pv[2][t] + pv[3][t];
        attn_vec[(size_t)(i * 2 + b) * DM + n * DH + t] = s;
    }
}

// ---------------- residual + layer-norm -------------------------------------
// out[r] = LN(a[r] + resid[r]) * g + b, row length DM=1024. grid 2048 rows.
__global__ __launch_bounds__(256) void ln_k(
    const float* __restrict__ a, const float* __restrict__ resid,
    const float* __restrict__ g, const float* __restrict__ bb,
    float* __restrict__ out)
{
    __shared__ float xs[DM];
    __shared__ float red[5];
    const int r = blockIdx.x;
    const int t = threadIdx.x;
    float lsum = 0.f;
    #pragma unroll
    for (int u = 0; u < 4; ++u) {
        int hdx = t + 256 * u;
        float x = a[(size_t)r * DM + hdx] + resid[(size_t)r * DM + hdx];
        xs[hdx] = x;
        lsum += x;
    }
    float m = block_reduce<false>(lsum, red, t) * (1.0f / DM);
    float lv = 0.f;
    #pragma unroll
    for (int u = 0; u < 4; ++u) {
        int hdx = t + 256 * u;
        float dd = xs[hdx] - m;
        lv += dd * dd;
    }
    float var = block_reduce<false>(lv, red, t) * (1.0f / DM);
    float rs = rsqrtf(var + 1e-12f);
    #pragma unroll
    for (int u = 0; u < 4; ++u) {
        int hdx = t + 256 * u;
        out[(size_t)r * DM + hdx] = (xs[hdx] - m) * rs * g[hdx] + bb[hdx];
    }
}

// ---------------- launch -----------------------------------------------------
extern "C" void kernel_launch(void* const* d_in, const int* in_sizes, int n_in,
                              void* d_out, int out_size, void* d_ws, size_t ws_size,
                              hipStream_t stream) {
    const float* h         = (const float*)d_in[0];
    const float* mems      = (const float*)d_in[1];
    const float* r         = (const float*)d_in[2];
    const float* seg_mat   = (const float*)d_in[3];
    // d_in[4] attn_mask: analytic (j > i + MLEN) is identical; not read.
    const float* wq        = (const float*)d_in[5];
    const float* wk        = (const float*)d_in[6];
    const float* wv        = (const float*)d_in[7];
    const float* wo        = (const float*)d_in[8];
    const float* wr        = (const float*)d_in[9];
    const float* rwb       = (const float*)d_in[10];
    const float* rrb       = (const float*)d_in[11];
    const float* rsb       = (const float*)d_in[12];
    const float* seg_embed = (const float*)d_in[13];
    const float* ln_g      = (const float*)d_in[14];
    const float* ln_b      = (const float*)d_in[15];
    const float* w1        = (const float*)d_in[16];
    const float* b1        = (const float*)d_in[17];
    const float* w2        = (const float*)d_in[18];
    const float* b2        = (const float*)d_in[19];
    const float* lf_g      = (const float*)d_in[20];
    const float* lf_b      = (const float*)d_in[21];
    float* out = (float*)d_out;
    float* ws  = (float*)d_ws;

    // workspace layout (floats, 1M = 2^20): total 22M floats = 88 MB
    const size_t M1 = 1u << 20;
    float* q_ws   = ws;            // [2048,1024]  2M
    float* k_ws   = ws + 2 * M1;   // [4096,1024]  4M
    float* v_ws   = ws + 6 * M1;   // [4096,1024]  4M
    float* kr_ws  = ws + 10 * M1;  // [6144,1024]  6M
    float* av_ws  = ws + 16 * M1;  // [2048,1024]  2M
    float* ao_ws  = ws + 18 * M1;  // [2048,1024]  2M
    float* oh_ws  = ws + 20 * M1;  // [2048,1024]  2M
    float* ff1_ws = ws + 10 * M1;  // [2048,4096]  8M (overlays kr+av; both dead)
    float* ff2_ws = ws;            // [2048,1024]  2M (overlays q; dead)

    dim3 blk(256);
    // projections
    gemm_k<0,false,0><<<dim3(16, 32), blk, 0, stream>>>(h,    nullptr, wq, nullptr, q_ws, 2048, 1024, 1024);
    gemm_k<1,false,0><<<dim3(16, 64), blk, 0, stream>>>(mems, h,       wk, nullptr, k_ws, 4096, 1024, 1024);
    gemm_k<1,false,0><<<dim3(16, 64), blk, 0, stream>>>(mems, h,       wv, nullptr, v_ws, 4096, 1024, 1024);
    gemm_k<0,false,0><<<dim3(16, 96), blk, 0, stream>>>(r,    nullptr, wr, nullptr, kr_ws, 6144, 1024, 1024);
    // fused relative attention -> attn_vec [2048, 1024]
    attn_k<<<dim3(QLEN, BSZ * NH), blk, 0, stream>>>(q_ws, k_ws, v_ws, kr_ws, seg_mat,
                                                     rwb, rrb, rsb, seg_embed, av_ws);
    // attn_out = attn_vec @ wo^T   (wo is [h, n*d] row-major -> B^T GEMM)
    gemm_k<0,true,0><<<dim3(16, 32), blk, 0, stream>>>(av_ws, nullptr, wo, nullptr, ao_ws, 2048, 1024, 1024);
    // out_h = LN(attn_out + h)
    ln_k<<<dim3(2048), blk, 0, stream>>>(ao_ws, h, ln_g, ln_b, oh_ws);
    // FFN
    gemm_k<0,false,1><<<dim3(64, 32), blk, 0, stream>>>(oh_ws,  nullptr, w1, b1, ff1_ws, 2048, 4096, 1024);
    gemm_k<0,false,2><<<dim3(16, 32), blk, 0, stream>>>(ff1_ws, nullptr, w2, b2, ff2_ws, 2048, 1024, 4096);
    // out = LN(ff + out_h)
    ln_k<<<dim3(2048), blk, 0, stream>>>(ff2_ws, oh_ws, lf_g, lf_b, out);
}

// Round 2
// 1717.215 us; speedup vs baseline: 3.4683x; 3.4683x over previous
//
#include <hip/hip_runtime.h>
#include <hip/hip_bf16.h>

// XLNet rel-attn layer + FFN. Round 2: MFMA bf16 flash attention.
// QLEN=1024 MLEN=1024 BSZ=2 DM=1024 NH=16 DH=64 DI=4096 KLEN=2048 RLEN=3072.
// rel_shift: bd_shifted[i,j] = bd_raw[i, QLEN-i+j].
// seg one-hot is rank-2: sm1[i,j] = qs[i] XOR ks[j] (extracted from seg_mat),
// so ef[i,j] = f0[i]*1 + f1[i]*ks[j], folded into QK^T MFMA as 2 k-features.

#define QLEN 1024
#define MLEN 1024
#define DM 1024
#define NH 16
#define DH 64
#define DI 4096
#define KLEN 2048
#define RLEN 3072

typedef __attribute__((ext_vector_type(8))) short s16x8;
typedef __attribute__((ext_vector_type(4))) float f32x4;
typedef unsigned short us;

__device__ __forceinline__ float bf2f(us u) {
    union { unsigned int i; float f; } x; x.i = ((unsigned int)u) << 16; return x.f;
}
__device__ __forceinline__ us f2bf(float f) {
    union { float f; unsigned int i; } x; x.f = f;
    return (us)((x.i + 0x7fffu + ((x.i >> 16) & 1u)) >> 16);
}
__device__ __forceinline__ void gload16(const void* g, void* lds) {
    __builtin_amdgcn_global_load_lds(
        (const __attribute__((address_space(1))) unsigned int*)g,
        (__attribute__((address_space(3))) unsigned int*)lds, 16, 0, 0);
}

// ---------------- block reduction (wave=64, 4 waves/block) ------------------
template<bool ISMAX>
__device__ __forceinline__ float block_reduce(float v, float* red, int t) {
    #pragma unroll
    for (int off = 32; off > 0; off >>= 1) {
        float o = __shfl_down(v, off);
        v = ISMAX ? fmaxf(v, o) : (v + o);
    }
    if ((t & 63) == 0) red[t >> 6] = v;
    __syncthreads();
    if (t == 0) {
        float s = red[0];
        #pragma unroll
        for (int w = 1; w < 4; ++w) s = ISMAX ? fmaxf(s, red[w]) : (s + red[w]);
        red[4] = s;
    }
    __syncthreads();
    return red[4];
}

// ---------------- fp32 tiled GEMM -------------------------------------------
// EPI: 0 none, 1 bias+gelu, 2 bias, 3 bf16 out scattered to [bn][seq][64].
template<int AMODE, bool BT, int EPI>
__global__ __launch_bounds__(256) void gemm_k(
    const float* __restrict__ A0, const float* __restrict__ A1,
    const float* __restrict__ B, const float* __restrict__ bias,
    float* __restrict__ C, int M, int N, int K)
{
    __shared__ float As[16][65];
    __shared__ float Bs[16][65];
    const int tid = threadIdx.x;
    const int tx = tid & 15, ty = tid >> 4;
    const int rowBase = blockIdx.y * 64;
    const int colBase = blockIdx.x * 64;
    float acc[4][4] = {};

    for (int k0 = 0; k0 < K; k0 += 16) {
        #pragma unroll
        for (int u = 0; u < 4; ++u) {
            int idx = tid + 256 * u;
            int ar = idx >> 4, ak = idx & 15;
            int grow = rowBase + ar;
            const float* arow;
            if (AMODE == 0) {
                arow = A0 + (size_t)grow * K;
            } else {
                int j = grow >> 1, b = grow & 1;
                arow = (j < MLEN) ? (A0 + (size_t)(j * 2 + b) * K)
                                  : (A1 + (size_t)((j - MLEN) * 2 + b) * K);
            }
            As[ak][ar] = arow[k0 + ak];
        }
        #pragma unroll
        for (int u = 0; u < 4; ++u) {
            int idx = tid + 256 * u;
            if (!BT) {
                int bk = idx >> 6, bnn = idx & 63;
                Bs[bk][bnn] = B[(size_t)(k0 + bk) * N + colBase + bnn];
            } else {
                int bnn = idx >> 4, bk = idx & 15;
                Bs[bk][bnn] = B[(size_t)(colBase + bnn) * K + k0 + bk];
            }
        }
        __syncthreads();
        #pragma unroll
        for (int kk = 0; kk < 16; ++kk) {
            float a0[4], b0[4];
            #pragma unroll
            for (int u = 0; u < 4; ++u) a0[u] = As[kk][ty * 4 + u];
            #pragma unroll
            for (int u = 0; u < 4; ++u) b0[u] = Bs[kk][tx * 4 + u];
            #pragma unroll
            for (int x = 0; x < 4; ++x)
                #pragma unroll
                for (int y = 0; y < 4; ++y)
                    acc[x][y] = fmaf(a0[x], b0[y], acc[x][y]);
        }
        __syncthreads();
    }

    #pragma unroll
    for (int x = 0; x < 4; ++x) {
        int rr = rowBase + ty * 4 + x;
        #pragma unroll
        for (int y = 0; y < 4; ++y) {
            int cc = colBase + tx * 4 + y;
            float v = acc[x][y];
            if (EPI == 1 || EPI == 2) v += bias[cc];
            if (EPI == 1) {
                float targ = 0.7978845608028654f * (v + 0.044715f * v * v * v);
                v = 0.5f * v * (1.0f + tanhf(targ));
            }
            if (EPI == 3) {
                int s = rr >> 1, bb = rr & 1, nn = cc >> 6, dd = cc & 63;
                ((us*)C)[(((size_t)(bb * 16 + nn)) * (size_t)(M >> 1) + s) * 64 + dd] = f2bf(v);
            } else {
                C[(size_t)rr * N + cc] = v;
            }
        }
    }
}

// ---------------- ks extraction: ks[b][j] = seg_mat[0,j,b,1] ----------------
__global__ __launch_bounds__(256) void ks_k(const float* __restrict__ seg, us* __restrict__ ksb) {
    int t = blockIdx.x * 256 + threadIdx.x;   // 4096
    int b = t >> 11, j = t & 2047;
    ksb[t] = f2bf(seg[(size_t)j * 4 + b * 2 + 1]);
}

// ---------------- Qx features: f0/f1 per (bn, i) -----------------------------
// E_s = dot(q[i]+rsb, seg_embed[s]); qs[i] = sm1[i,0] XOR sm1[0,0];
// f0 = E0 + qs*(E1-E0);  f1 = (E1-E0)*(1-2qs).
__global__ __launch_bounds__(256) void eqx_k(
    const us* __restrict__ qb, const float* __restrict__ rsb,
    const float* __restrict__ se, const float* __restrict__ seg,
    float* __restrict__ Qx)
{
    int task = blockIdx.x * 4 + (threadIdx.x >> 6);  // 0..32767
    int l = threadIdx.x & 63;
    int bn = task >> 10, i = task & 1023;
    int b = bn >> 4, n = bn & 15;
    float q = bf2f(qb[((size_t)bn * QLEN + i) * DH + l]) + rsb[n * DH + l];
    float e0 = q * se[(0 * NH + n) * DH + l];
    float e1 = q * se[(1 * NH + n) * DH + l];
    #pragma unroll
    for (int off = 32; off > 0; off >>= 1) {
        e0 += __shfl_xor(e0, off);
        e1 += __shfl_xor(e1, off);
    }
    if (l == 0) {
        float qsI = seg[(size_t)i * 8192 + b * 2 + 1];
        float qs0 = seg[b * 2 + 1];
        float qs = (qsI != qs0) ? 1.f : 0.f;
        float ed = e1 - e0;
        Qx[((size_t)bn * QLEN + i) * 2 + 0] = e0 + qs * ed;
        Qx[((size_t)bn * QLEN + i) * 2 + 1] = ed * (1.f - 2.f * qs);
    }
}

// ---------------- MFMA flash attention --------------------------------------
// grid (16 i-tiles of 64, 32 bn), 256 threads = 4 waves, wave w owns q-rows
// [i0+w*16, i0+w*16+16). Computes S^T tiles [64 j][16 m] per wave.
__global__ __launch_bounds__(256) void attn2_k(
    const us* __restrict__ qb, const us* __restrict__ kb, const us* __restrict__ vb,
    const us* __restrict__ krb, const us* __restrict__ ksb, const float* __restrict__ Qx,
    const float* __restrict__ rwb, const float* __restrict__ rrb,
    float* __restrict__ av)
{
    __shared__ us K_lds[64 * 64];      // [j][d] chunk-XOR swizzled
    __shared__ us KR_lds[128 * 64];    // union band, same swizzle
    __shared__ us VT_lds[64 * 64];     // [d][j] swizzled
    __shared__ float G_lds[4 * 80 * 16];
    __shared__ us P_lds[4 * 16 * 64];  // per-wave [m][j] swizzled

    const int tid = threadIdx.x;
    const int w = tid >> 6, l = tid & 63;
    const int lm = l & 15, lg = l >> 4;
    const int i0 = blockIdx.x * 64;
    const int bn = blockIdx.y;
    const int b = bn >> 4, n = bn & 15;
    const int i = i0 + w * 16 + lm;    // q-row for this lane's S^T column

    // hoisted Q fragments (B-operand: lane holds Q[m=lm][k=(lg)*8+e])
    s16x8 qwf[2], qrf[2], qxf;
    {
        const us* qrow = qb + ((size_t)bn * QLEN + i) * DH;
        #pragma unroll
        for (int ks = 0; ks < 2; ++ks) {
            s16x8 v = *(const s16x8*)(qrow + ks * 32 + lg * 8);
            #pragma unroll
            for (int e = 0; e < 8; ++e) {
                int d = ks * 32 + lg * 8 + e;
                float f = bf2f((us)v[e]);
                qwf[ks][e] = (short)f2bf(f + rwb[n * DH + d]);
                qrf[ks][e] = (short)f2bf(f + rrb[n * DH + d]);
            }
        }
        #pragma unroll
        for (int e = 0; e < 8; ++e) qxf[e] = 0;
        if (lg == 0) {
            qxf[0] = (short)f2bf(Qx[((size_t)bn * QLEN + i) * 2 + 0]);
            qxf[1] = (short)f2bf(Qx[((size_t)bn * QLEN + i) * 2 + 1]);
        }
    }

    f32x4 of[4] = {{0,0,0,0},{0,0,0,0},{0,0,0,0},{0,0,0,0}};
    float M = -3.0e38f, L = 0.f;
    float* gw = &G_lds[w * 1280];
    us* pw = &P_lds[w * 1024];

    int njt = ((i0 + 63 + MLEN) >> 6) + 1;
    if (njt > 32) njt = 32;

    for (int jt = 0; jt < njt; ++jt) {
        const int j0 = jt * 64;
        if (jt) __syncthreads();
        // stage K tile [64][64]: global_load_lds w/ pre-swizzled source
        #pragma unroll
        for (int u = 0; u < 2; ++u) {
            int c = (w * 2 + u) * 64 + l;
            int row = c >> 3, ch = c & 7;
            gload16(kb + ((size_t)bn * KLEN + j0 + row) * DH + (size_t)((ch ^ (row & 7)) * 8),
                    &K_lds[(w * 2 + u) * 512]);
        }
        // stage KR union band [128][64]; rows [ur0, ur0+128) all in [1, 3072)
        const int ur0 = QLEN - i0 - 63 + j0;
        #pragma unroll
        for (int u = 0; u < 4; ++u) {
            int c = (w * 4 + u) * 64 + l;
            int row = c >> 3, ch = c & 7;
            gload16(krb + ((size_t)bn * RLEN + ur0 + row) * DH + (size_t)((ch ^ (row & 7)) * 8),
                    &KR_lds[(w * 4 + u) * 512]);
        }
        // stage V transposed: thread reads 16B of a V row, scatters to VT[d][j]
        #pragma unroll
        for (int u = 0; u < 2; ++u) {
            int j = l;
            int cd = w + u * 4;
            s16x8 vv = *(const s16x8*)(vb + ((size_t)bn * KLEN + j0 + j) * DH + cd * 8);
            #pragma unroll
            for (int e = 0; e < 8; ++e) {
                int d = cd * 8 + e;
                VT_lds[d * 64 + (((j * 2) ^ ((d & 7) << 4)) >> 1)] = (us)vv[e];
            }
        }
        __syncthreads();

        // ---- ac + ef: S^T[j, m] fragments (A = K rows, B = Q) ----
        f32x4 sf[4];
        #pragma unroll
        for (int f = 0; f < 4; ++f) {
            f32x4 cfr = {0, 0, 0, 0};
            int row = f * 16 + lm;
            #pragma unroll
            for (int ks = 0; ks < 2; ++ks) {
                s16x8 a = *(const s16x8*)&K_lds[row * 64 + (((ks * 64 + lg * 16) ^ ((row & 7) << 4)) >> 1)];
                cfr = __builtin_amdgcn_mfma_f32_16x16x32_bf16(a, qwf[ks], cfr, 0, 0, 0);
            }
            s16x8 aext;
            #pragma unroll
            for (int e = 0; e < 8; ++e) aext[e] = 0;
            if (lg == 0) {
                aext[0] = (short)0x3F80;  // 1.0 bf16
                aext[1] = (short)ksb[b * KLEN + j0 + f * 16 + lm];
            }
            cfr = __builtin_amdgcn_mfma_f32_16x16x32_bf16(aext, qxf, cfr, 0, 0, 0);
            sf[f] = cfr;
        }

        // ---- bd: banded G^T = KR_band x Qr^T, then diagonal extraction ----
        const int woff = 48 - w * 16;
        #pragma unroll
        for (int pf = 0; pf < 5; ++pf) {
            f32x4 g = {0, 0, 0, 0};
            int row = woff + pf * 16 + lm;
            #pragma unroll
            for (int ks = 0; ks < 2; ++ks) {
                s16x8 a = *(const s16x8*)&KR_lds[row * 64 + (((ks * 64 + lg * 16) ^ ((row & 7) << 4)) >> 1)];
                g = __builtin_amdgcn_mfma_f32_16x16x32_bf16(a, qrf[ks], g, 0, 0, 0);
            }
            #pragma unroll
            for (int rr = 0; rr < 4; ++rr)
                gw[(pf * 16 + lg * 4 + rr) * 16 + lm] = g[rr];
        }

        // ---- combine, mask, online softmax ----
        float sv[16];
        float tmax = -3.0e38f;
        #pragma unroll
        for (int f = 0; f < 4; ++f) {
            #pragma unroll
            for (int rr = 0; rr < 4; ++rr) {
                int jl = f * 16 + lg * 4 + rr;
                float bd = gw[(jl + 15 - lm) * 16 + lm];   // p = jl + 15 - mm
                float s = (sf[f][rr] + bd) * 0.125f;
                if (j0 + jl > i + MLEN) s = -1.0e30f;
                sv[f * 4 + rr] = s;
                tmax = fmaxf(tmax, s);
            }
        }
        tmax = fmaxf(tmax, __shfl_xor(tmax, 16));
        tmax = fmaxf(tmax, __shfl_xor(tmax, 32));
        float Mnew = fmaxf(M, tmax);
        float scale = __expf(M - Mnew);
        float psum = 0.f;
        unsigned int pk[8];
        #pragma unroll
        for (int f = 0; f < 4; ++f) {
            #pragma unroll
            for (int rp = 0; rp < 2; ++rp) {
                float p0 = __expf(sv[f * 4 + rp * 2] - Mnew);
                float p1 = __expf(sv[f * 4 + rp * 2 + 1] - Mnew);
                psum += p0 + p1;
                pk[f * 2 + rp] = (unsigned int)f2bf(p0) | ((unsigned int)f2bf(p1) << 16);
            }
        }
        psum += __shfl_xor(psum, 16);
        psum += __shfl_xor(psum, 32);
        L = L * scale + psum;
        M = Mnew;
        // rescale O (its rows live at m' = lg*4+rr -> fetch scale via bpermute)
        float rs4[4];
        #pragma unroll
        for (int rr = 0; rr < 4; ++rr)
            rs4[rr] = __shfl(scale, (l & 48) | (lg * 4 + rr));
        #pragma unroll
        for (int df = 0; df < 4; ++df)
            #pragma unroll
            for (int rr = 0; rr < 4; ++rr)
                of[df][rr] *= rs4[rr];
        // stage P^T fragments to P_lds[m][j] (packed b32 writes)
        #pragma unroll
        for (int f = 0; f < 4; ++f) {
            #pragma unroll
            for (int rp = 0; rp < 2; ++rp) {
                int jl2 = f * 16 + lg * 4 + rp * 2;
                *(unsigned int*)&pw[lm * 64 + (((jl2 * 2) ^ ((lm & 7) << 4)) >> 1)] = pk[f * 2 + rp];
            }
        }
        // ---- PV: O[m][d] += P x V (A = P rows from LDS, B = V^T) ----
        #pragma unroll
        for (int ks = 0; ks < 2; ++ks) {
            s16x8 pa = *(const s16x8*)&pw[lm * 64 + (((ks * 64 + lg * 16) ^ ((lm & 7) << 4)) >> 1)];
            #pragma unroll
            for (int df = 0; df < 4; ++df) {
                int drow = df * 16 + lm;
                s16x8 vB = *(const s16x8*)&VT_lds[drow * 64 + (((ks * 64 + lg * 16) ^ ((lm & 7) << 4)) >> 1)];
                of[df] = __builtin_amdgcn_mfma_f32_16x16x32_bf16(pa, vB, of[df], 0, 0, 0);
            }
        }
    }

    // epilogue: O rows m' = lg*4+rr, cols d = df*16+lm; divide by L(m')
    float rl4[4];
    #pragma unroll
    for (int rr = 0; rr < 4; ++rr)
        rl4[rr] = __shfl(L, (l & 48) | (lg * 4 + rr));
    #pragma unroll
    for (int df = 0; df < 4; ++df) {
        #pragma unroll
        for (int rr = 0; rr < 4; ++rr) {
            int m2 = lg * 4 + rr;
            int d = df * 16 + lm;
            int irow = i0 + w * 16 + m2;
            av[((size_t)irow * 2 + b) * DM + n * DH + d] = of[df][rr] / rl4[rr];
        }
    }
}

// ---------------- residual + layer-norm -------------------------------------
__global__ __launch_bounds__(256) void ln_k(
    const float* __restrict__ a, const float* __restrict__ resid,
    const float* __restrict__ g, const float* __restrict__ bb,
    float* __restrict__ out)
{
    __shared__ float xs[DM];
    __shared__ float red[5];
    const int r = blockIdx.x;
    const int t = threadIdx.x;
    float lsum = 0.f;
    #pragma unroll
    for (int u = 0; u < 4; ++u) {
        int hdx = t + 256 * u;
        float x = a[(size_t)r * DM + hdx] + resid[(size_t)r * DM + hdx];
        xs[hdx] = x;
        lsum += x;
    }
    float m = block_reduce<false>(lsum, red, t) * (1.0f / DM);
    float lv = 0.f;
    #pragma unroll
    for (int u = 0; u < 4; ++u) {
        int hdx = t + 256 * u;
        float dd = xs[hdx] - m;
        lv += dd * dd;
    }
    float var = block_reduce<false>(lv, red, t) * (1.0f / DM);
    float rs = rsqrtf(var + 1e-12f);
    #pragma unroll
    for (int u = 0; u < 4; ++u) {
        int hdx = t + 256 * u;
        out[(size_t)r * DM + hdx] = (xs[hdx] - m) * rs * g[hdx] + bb[hdx];
    }
}

// ---------------- launch -----------------------------------------------------
extern "C" void kernel_launch(void* const* d_in, const int* in_sizes, int n_in,
                              void* d_out, int out_size, void* d_ws, size_t ws_size,
                              hipStream_t stream) {
    const float* h         = (const float*)d_in[0];
    const float* mems      = (const float*)d_in[1];
    const float* r         = (const float*)d_in[2];
    const float* seg_mat   = (const float*)d_in[3];
    const float* wq        = (const float*)d_in[5];
    const float* wk        = (const float*)d_in[6];
    const float* wv        = (const float*)d_in[7];
    const float* wo        = (const float*)d_in[8];
    const float* wr        = (const float*)d_in[9];
    const float* rwb       = (const float*)d_in[10];
    const float* rrb       = (const float*)d_in[11];
    const float* rsb       = (const float*)d_in[12];
    const float* seg_embed = (const float*)d_in[13];
    const float* ln_g      = (const float*)d_in[14];
    const float* ln_b      = (const float*)d_in[15];
    const float* w1        = (const float*)d_in[16];
    const float* b1        = (const float*)d_in[17];
    const float* w2        = (const float*)d_in[18];
    const float* b2        = (const float*)d_in[19];
    const float* lf_g      = (const float*)d_in[20];
    const float* lf_b      = (const float*)d_in[21];
    float* out = (float*)d_out;
    char* W = (char*)d_ws;

    // byte layout (66 MB total; round-1 proved >=88 MB available)
    us*    q_bf  = (us*)(W);                         // 4 MB  [32][1024][64]
    us*    k_bf  = (us*)(W + (4ull  << 20));         // 8 MB  [32][2048][64]
    us*    v_bf  = (us*)(W + (12ull << 20));         // 8 MB
    us*    kr_bf = (us*)(W + (20ull << 20));         // 12 MB [32][3072][64]
    float* Qx    = (float*)(W + (32ull << 20));      // 256 KB
    us*    ks_bf = (us*)(W + (33ull << 20));         // 8 KB
    float* av    = (float*)(W + (34ull << 20));      // 8 MB
    float* ao    = (float*)(W + (42ull << 20));      // 8 MB
    float* oh    = (float*)(W + (50ull << 20));      // 8 MB
    float* ff2   = (float*)(W + (58ull << 20));      // 8 MB
    float* ff1   = (float*)(W);                      // 32 MB overlay (q..kr dead)

    dim3 blk(256);
    // projections -> bf16 [bn][seq][64]
    gemm_k<0,false,3><<<dim3(16, 32), blk, 0, stream>>>(h,    nullptr, wq, nullptr, (float*)q_bf, 2048, 1024, 1024);
    gemm_k<1,false,3><<<dim3(16, 64), blk, 0, stream>>>(mems, h,       wk, nullptr, (float*)k_bf, 4096, 1024, 1024);
    gemm_k<1,false,3><<<dim3(16, 64), blk, 0, stream>>>(mems, h,       wv, nullptr, (float*)v_bf, 4096, 1024, 1024);
    gemm_k<0,false,3><<<dim3(16, 96), blk, 0, stream>>>(r,    nullptr, wr, nullptr, (float*)kr_bf, 6144, 1024, 1024);
    // seg features
    ks_k<<<dim3(16), blk, 0, stream>>>(seg_mat, ks_bf);
    eqx_k<<<dim3(8192), blk, 0, stream>>>(q_bf, rsb, seg_embed, seg_mat, Qx);
    // fused MFMA attention -> av [i*2+b][n*64+d] f32
    attn2_k<<<dim3(16, 32), blk, 0, stream>>>(q_bf, k_bf, v_bf, kr_bf, ks_bf, Qx, rwb, rrb, av);
    // attn_out = av @ wo^T
    gemm_k<0,true,0><<<dim3(16, 32), blk, 0, stream>>>(av, nullptr, wo, nullptr, ao, 2048, 1024, 1024);
    ln_k<<<dim3(2048), blk, 0, stream>>>(ao, h, ln_g, ln_b, oh);
    // FFN
    gemm_k<0,false,1><<<dim3(64, 32), blk, 0, stream>>>(oh,  nullptr, w1, b1, ff1, 2048, 4096, 1024);
    gemm_k<0,false,2><<<dim3(16, 32), blk, 0, stream>>>(ff1, nullptr, w2, b2, ff2, 2048, 1024, 4096);
    ln_k<<<dim3(2048), blk, 0, stream>>>(ff2, oh, lf_g, lf_b, out);
}

// Round 3
// 514.315 us; speedup vs baseline: 11.5802x; 3.3388x over previous
//
#include <hip/hip_runtime.h>
#include <hip/hip_bf16.h>

// XLNet rel-attn layer + FFN. Round 3: all GEMMs on bf16 MFMA.
// QLEN=1024 MLEN=1024 BSZ=2 DM=1024 NH=16 DH=64 DI=4096 KLEN=2048 RLEN=3072.

#define QLEN 1024
#define MLEN 1024
#define DM 1024
#define NH 16
#define DH 64
#define DI 4096
#define KLEN 2048
#define RLEN 3072

typedef __attribute__((ext_vector_type(8))) short s16x8;
typedef __attribute__((ext_vector_type(4))) float f32x4;
typedef unsigned short us;

__device__ __forceinline__ float bf2f(us u) {
    union { unsigned int i; float f; } x; x.i = ((unsigned int)u) << 16; return x.f;
}
__device__ __forceinline__ us f2bf(float f) {
    union { float f; unsigned int i; } x; x.f = f;
    return (us)((x.i + 0x7fffu + ((x.i >> 16) & 1u)) >> 16);
}
__device__ __forceinline__ void gload16(const void* g, void* lds) {
    __builtin_amdgcn_global_load_lds(
        (const __attribute__((address_space(1))) unsigned int*)g,
        (__attribute__((address_space(3))) unsigned int*)lds, 16, 0, 0);
}

// ---------------- block reduction (wave=64, 4 waves/block) ------------------
template<bool ISMAX>
__device__ __forceinline__ float block_reduce(float v, float* red, int t) {
    #pragma unroll
    for (int off = 32; off > 0; off >>= 1) {
        float o = __shfl_down(v, off);
        v = ISMAX ? fmaxf(v, o) : (v + o);
    }
    if ((t & 63) == 0) red[t >> 6] = v;
    __syncthreads();
    if (t == 0) {
        float s = red[0];
        #pragma unroll
        for (int w = 1; w < 4; ++w) s = ISMAX ? fmaxf(s, red[w]) : (s + red[w]);
        red[4] = s;
    }
    __syncthreads();
    return red[4];
}

// ---------------- fp32 -> bf16 convert --------------------------------------
__global__ __launch_bounds__(256) void conv_k(const float* __restrict__ in,
                                              us* __restrict__ out, int n8) {
    int t = blockIdx.x * 256 + threadIdx.x;
    if (t >= n8) return;
    const float4* p = (const float4*)in + 2 * (size_t)t;
    float4 a = p[0], b = p[1];
    us o[8] = { f2bf(a.x), f2bf(a.y), f2bf(a.z), f2bf(a.w),
                f2bf(b.x), f2bf(b.y), f2bf(b.z), f2bf(b.w) };
    *((uint4*)out + t) = *(const uint4*)o;
}

// ---------------- fp32 -> bf16 transpose-convert: out[C][R] = in[R][C]^T ----
__global__ __launch_bounds__(256) void tconv_k(const float* __restrict__ in,
                                               us* __restrict__ out, int R, int C) {
    __shared__ us t[64][65];
    const int tid = threadIdx.x;
    const int c0 = blockIdx.x * 64, r0 = blockIdx.y * 64;
    #pragma unroll
    for (int u = 0; u < 16; ++u) {
        int idx = tid + 256 * u;
        int rr = idx >> 6, cc = idx & 63;
        t[cc][rr] = f2bf(in[(size_t)(r0 + rr) * C + c0 + cc]);
    }
    __syncthreads();
    #pragma unroll
    for (int u = 0; u < 16; ++u) {
        int idx = tid + 256 * u;
        int rr = idx >> 6, cc = idx & 63;
        out[(size_t)(c0 + rr) * R + r0 + cc] = t[rr][cc];
    }
}

// ---------------- bf16 MFMA GEMM: C[M,N] = A[M,K] @ Bt[N,K]^T ---------------
// 128x128 tile, BK=32, 4 waves 2x2 (64x64 each, 4x4 16x16x32 fragments).
// LDS chunk-major [kc][row][8] so fragment ds_read_b128 is 2-way (free) and
// global_load_lds dest stays linear (source uses the same chunk mapping).
// EPI: 0 f32 out, 1 bias+gelu->bf16, 2 bias->f32, 3 bf16 scatter [bn][seq][64]
template<int EPI>
__global__ __launch_bounds__(256) void gemm_mfma(
    const us* __restrict__ A, const us* __restrict__ Bt,
    const float* __restrict__ bias, void* __restrict__ Cout,
    int M, int N, int K)
{
    __shared__ us As[128 * 32];
    __shared__ us Bs[128 * 32];
    const int tid = threadIdx.x;
    const int w = tid >> 6, l = tid & 63;
    const int lm = l & 15, lg = l >> 4;
    const int m0 = blockIdx.y * 128, n0 = blockIdx.x * 128;
    const int wr = (w >> 1) * 64, wc = (w & 1) * 64;
    f32x4 acc[4][4] = {};

    // per-thread staging coordinates (2 issues each for A and B)
    int c0_ = w * 64, c1_ = 256 + w * 64;
    int row0 = (c0_ + l) & 127, kc0 = (c0_ + l) >> 7;
    int row1 = (c1_ + l) & 127, kc1 = (c1_ + l) >> 7;

    for (int k0 = 0; k0 < K; k0 += 32) {
        __syncthreads();
        gload16(A  + (size_t)(m0 + row0) * K + k0 + kc0 * 8, &As[c0_ * 8]);
        gload16(Bt + (size_t)(n0 + row0) * K + k0 + kc0 * 8, &Bs[c0_ * 8]);
        gload16(A  + (size_t)(m0 + row1) * K + k0 + kc1 * 8, &As[c1_ * 8]);
        gload16(Bt + (size_t)(n0 + row1) * K + k0 + kc1 * 8, &Bs[c1_ * 8]);
        __syncthreads();
        s16x8 af[4], bfr[4];
        #pragma unroll
        for (int mf = 0; mf < 4; ++mf)
            af[mf] = *(const s16x8*)&As[(lg * 128 + wr + mf * 16 + lm) * 8];
        #pragma unroll
        for (int nf = 0; nf < 4; ++nf)
            bfr[nf] = *(const s16x8*)&Bs[(lg * 128 + wc + nf * 16 + lm) * 8];
        #pragma unroll
        for (int mf = 0; mf < 4; ++mf)
            #pragma unroll
            for (int nf = 0; nf < 4; ++nf)
                acc[mf][nf] = __builtin_amdgcn_mfma_f32_16x16x32_bf16(
                    af[mf], bfr[nf], acc[mf][nf], 0, 0, 0);
    }

    #pragma unroll
    for (int mf = 0; mf < 4; ++mf) {
        #pragma unroll
        for (int nf = 0; nf < 4; ++nf) {
            #pragma unroll
            for (int rr = 0; rr < 4; ++rr) {
                int row = m0 + wr + mf * 16 + lg * 4 + rr;
                int col = n0 + wc + nf * 16 + lm;
                float v = acc[mf][nf][rr];
                if (EPI == 1 || EPI == 2) v += bias[col];
                if (EPI == 1) {
                    float targ = 0.7978845608028654f * (v + 0.044715f * v * v * v);
                    v = 0.5f * v * (1.0f + tanhf(targ));
                }
                if (EPI == 0 || EPI == 2) {
                    ((float*)Cout)[(size_t)row * N + col] = v;
                } else if (EPI == 1) {
                    ((us*)Cout)[(size_t)row * N + col] = f2bf(v);
                } else {
                    int s = row >> 1, bb = row & 1, nn = col >> 6, dd = col & 63;
                    ((us*)Cout)[(((size_t)(bb * 16 + nn)) * (size_t)(M >> 1) + s) * 64 + dd] = f2bf(v);
                }
            }
        }
    }
}

// ---------------- ks extraction: ks[b][j] = seg_mat[0,j,b,1] ----------------
__global__ __launch_bounds__(256) void ks_k(const float* __restrict__ seg, us* __restrict__ ksb) {
    int t = blockIdx.x * 256 + threadIdx.x;   // 4096
    int b = t >> 11, j = t & 2047;
    ksb[t] = f2bf(seg[(size_t)j * 4 + b * 2 + 1]);
}

// ---------------- Qx features: f0/f1 per (bn, i) -----------------------------
__global__ __launch_bounds__(256) void eqx_k(
    const us* __restrict__ qb, const float* __restrict__ rsb,
    const float* __restrict__ se, const float* __restrict__ seg,
    float* __restrict__ Qx)
{
    int task = blockIdx.x * 4 + (threadIdx.x >> 6);  // 0..32767
    int l = threadIdx.x & 63;
    int bn = task >> 10, i = task & 1023;
    int b = bn >> 4, n = bn & 15;
    float q = bf2f(qb[((size_t)bn * QLEN + i) * DH + l]) + rsb[n * DH + l];
    float e0 = q * se[(0 * NH + n) * DH + l];
    float e1 = q * se[(1 * NH + n) * DH + l];
    #pragma unroll
    for (int off = 32; off > 0; off >>= 1) {
        e0 += __shfl_xor(e0, off);
        e1 += __shfl_xor(e1, off);
    }
    if (l == 0) {
        float qsI = seg[(size_t)i * 8192 + b * 2 + 1];
        float qs0 = seg[b * 2 + 1];
        float qs = (qsI != qs0) ? 1.f : 0.f;
        float ed = e1 - e0;
        Qx[((size_t)bn * QLEN + i) * 2 + 0] = e0 + qs * ed;
        Qx[((size_t)bn * QLEN + i) * 2 + 1] = ed * (1.f - 2.f * qs);
    }
}

// ---------------- MFMA flash attention --------------------------------------
__global__ __launch_bounds__(256) void attn2_k(
    const us* __restrict__ qb, const us* __restrict__ kb, const us* __restrict__ vb,
    const us* __restrict__ krb, const us* __restrict__ ksb, const float* __restrict__ Qx,
    const float* __restrict__ rwb, const float* __restrict__ rrb,
    us* __restrict__ av)
{
    __shared__ us K_lds[64 * 64];
    __shared__ us KR_lds[128 * 64];
    __shared__ us VT_lds[64 * 64];
    __shared__ float G_lds[4 * 80 * 16];
    __shared__ us P_lds[4 * 16 * 64];

    const int tid = threadIdx.x;
    const int w = tid >> 6, l = tid & 63;
    const int lm = l & 15, lg = l >> 4;
    const int i0 = blockIdx.x * 64;
    const int bn = blockIdx.y;
    const int b = bn >> 4, n = bn & 15;
    const int i = i0 + w * 16 + lm;

    s16x8 qwf[2], qrf[2], qxf;
    {
        const us* qrow = qb + ((size_t)bn * QLEN + i) * DH;
        #pragma unroll
        for (int ks = 0; ks < 2; ++ks) {
            s16x8 v = *(const s16x8*)(qrow + ks * 32 + lg * 8);
            #pragma unroll
            for (int e = 0; e < 8; ++e) {
                int d = ks * 32 + lg * 8 + e;
                float f = bf2f((us)v[e]);
                qwf[ks][e] = (short)f2bf(f + rwb[n * DH + d]);
                qrf[ks][e] = (short)f2bf(f + rrb[n * DH + d]);
            }
        }
        #pragma unroll
        for (int e = 0; e < 8; ++e) qxf[e] = 0;
        if (lg == 0) {
            qxf[0] = (short)f2bf(Qx[((size_t)bn * QLEN + i) * 2 + 0]);
            qxf[1] = (short)f2bf(Qx[((size_t)bn * QLEN + i) * 2 + 1]);
        }
    }

    f32x4 of[4] = {{0,0,0,0},{0,0,0,0},{0,0,0,0},{0,0,0,0}};
    float M = -3.0e38f, L = 0.f;
    float* gw = &G_lds[w * 1280];
    us* pw = &P_lds[w * 1024];

    int njt = ((i0 + 63 + MLEN) >> 6) + 1;
    if (njt > 32) njt = 32;

    for (int jt = 0; jt < njt; ++jt) {
        const int j0 = jt * 64;
        if (jt) __syncthreads();
        #pragma unroll
        for (int u = 0; u < 2; ++u) {
            int c = (w * 2 + u) * 64 + l;
            int row = c >> 3, ch = c & 7;
            gload16(kb + ((size_t)bn * KLEN + j0 + row) * DH + (size_t)((ch ^ (row & 7)) * 8),
                    &K_lds[(w * 2 + u) * 512]);
        }
        const int ur0 = QLEN - i0 - 63 + j0;
        #pragma unroll
        for (int u = 0; u < 4; ++u) {
            int c = (w * 4 + u) * 64 + l;
            int row = c >> 3, ch = c & 7;
            gload16(krb + ((size_t)bn * RLEN + ur0 + row) * DH + (size_t)((ch ^ (row & 7)) * 8),
                    &KR_lds[(w * 4 + u) * 512]);
        }
        #pragma unroll
        for (int u = 0; u < 2; ++u) {
            int j = l;
            int cd = w + u * 4;
            s16x8 vv = *(const s16x8*)(vb + ((size_t)bn * KLEN + j0 + j) * DH + cd * 8);
            #pragma unroll
            for (int e = 0; e < 8; ++e) {
                int d = cd * 8 + e;
                VT_lds[d * 64 + (((j * 2) ^ ((d & 7) << 4)) >> 1)] = (us)vv[e];
            }
        }
        __syncthreads();

        f32x4 sf[4];
        #pragma unroll
        for (int f = 0; f < 4; ++f) {
            f32x4 cfr = {0, 0, 0, 0};
            int row = f * 16 + lm;
            #pragma unroll
            for (int ks = 0; ks < 2; ++ks) {
                s16x8 a = *(const s16x8*)&K_lds[row * 64 + (((ks * 64 + lg * 16) ^ ((row & 7) << 4)) >> 1)];
                cfr = __builtin_amdgcn_mfma_f32_16x16x32_bf16(a, qwf[ks], cfr, 0, 0, 0);
            }
            s16x8 aext;
            #pragma unroll
            for (int e = 0; e < 8; ++e) aext[e] = 0;
            if (lg == 0) {
                aext[0] = (short)0x3F80;
                aext[1] = (short)ksb[b * KLEN + j0 + f * 16 + lm];
            }
            cfr = __builtin_amdgcn_mfma_f32_16x16x32_bf16(aext, qxf, cfr, 0, 0, 0);
            sf[f] = cfr;
        }

        const int woff = 48 - w * 16;
        #pragma unroll
        for (int pf = 0; pf < 5; ++pf) {
            f32x4 g = {0, 0, 0, 0};
            int row = woff + pf * 16 + lm;
            #pragma unroll
            for (int ks = 0; ks < 2; ++ks) {
                s16x8 a = *(const s16x8*)&KR_lds[row * 64 + (((ks * 64 + lg * 16) ^ ((row & 7) << 4)) >> 1)];
                g = __builtin_amdgcn_mfma_f32_16x16x32_bf16(a, qrf[ks], g, 0, 0, 0);
            }
            #pragma unroll
            for (int rr = 0; rr < 4; ++rr)
                gw[(pf * 16 + lg * 4 + rr) * 16 + lm] = g[rr];
        }

        float sv[16];
        float tmax = -3.0e38f;
        #pragma unroll
        for (int f = 0; f < 4; ++f) {
            #pragma unroll
            for (int rr = 0; rr < 4; ++rr) {
                int jl = f * 16 + lg * 4 + rr;
                float bd = gw[(jl + 15 - lm) * 16 + lm];
                float s = (sf[f][rr] + bd) * 0.125f;
                if (j0 + jl > i + MLEN) s = -1.0e30f;
                sv[f * 4 + rr] = s;
                tmax = fmaxf(tmax, s);
            }
        }
        tmax = fmaxf(tmax, __shfl_xor(tmax, 16));
        tmax = fmaxf(tmax, __shfl_xor(tmax, 32));
        float Mnew = fmaxf(M, tmax);
        float scale = __expf(M - Mnew);
        float psum = 0.f;
        unsigned int pk[8];
        #pragma unroll
        for (int f = 0; f < 4; ++f) {
            #pragma unroll
            for (int rp = 0; rp < 2; ++rp) {
                float p0 = __expf(sv[f * 4 + rp * 2] - Mnew);
                float p1 = __expf(sv[f * 4 + rp * 2 + 1] - Mnew);
                psum += p0 + p1;
                pk[f * 2 + rp] = (unsigned int)f2bf(p0) | ((unsigned int)f2bf(p1) << 16);
            }
        }
        psum += __shfl_xor(psum, 16);
        psum += __shfl_xor(psum, 32);
        L = L * scale + psum;
        M = Mnew;
        float rs4[4];
        #pragma unroll
        for (int rr = 0; rr < 4; ++rr)
            rs4[rr] = __shfl(scale, (l & 48) | (lg * 4 + rr));
        #pragma unroll
        for (int df = 0; df < 4; ++df)
            #pragma unroll
            for (int rr = 0; rr < 4; ++rr)
                of[df][rr] *= rs4[rr];
        #pragma unroll
        for (int f = 0; f < 4; ++f) {
            #pragma unroll
            for (int rp = 0; rp < 2; ++rp) {
                int jl2 = f * 16 + lg * 4 + rp * 2;
                *(unsigned int*)&pw[lm * 64 + (((jl2 * 2) ^ ((lm & 7) << 4)) >> 1)] = pk[f * 2 + rp];
            }
        }
        #pragma unroll
        for (int ks = 0; ks < 2; ++ks) {
            s16x8 pa = *(const s16x8*)&pw[lm * 64 + (((ks * 64 + lg * 16) ^ ((lm & 7) << 4)) >> 1)];
            #pragma unroll
            for (int df = 0; df < 4; ++df) {
                int drow = df * 16 + lm;
                s16x8 vB = *(const s16x8*)&VT_lds[drow * 64 + (((ks * 64 + lg * 16) ^ ((lm & 7) << 4)) >> 1)];
                of[df] = __builtin_amdgcn_mfma_f32_16x16x32_bf16(pa, vB, of[df], 0, 0, 0);
            }
        }
    }

    float rl4[4];
    #pragma unroll
    for (int rr = 0; rr < 4; ++rr)
        rl4[rr] = __shfl(L, (l & 48) | (lg * 4 + rr));
    #pragma unroll
    for (int df = 0; df < 4; ++df) {
        #pragma unroll
        for (int rr = 0; rr < 4; ++rr) {
            int m2 = lg * 4 + rr;
            int d = df * 16 + lm;
            int irow = i0 + w * 16 + m2;
            av[((size_t)irow * 2 + b) * DM + n * DH + d] = f2bf(of[df][rr] / rl4[rr]);
        }
    }
}

// ---------------- residual + layer-norm -------------------------------------
template<bool RESBF, bool OUTBF>
__global__ __launch_bounds__(256) void ln_k(
    const float* __restrict__ a, const void* __restrict__ resid,
    const float* __restrict__ g, const float* __restrict__ bb,
    void* __restrict__ out)
{
    __shared__ float xs[DM];
    __shared__ float red[5];
    const int r = blockIdx.x;
    const int t = threadIdx.x;
    float lsum = 0.f;
    #pragma unroll
    for (int u = 0; u < 4; ++u) {
        int hdx = t + 256 * u;
        float rv = RESBF ? bf2f(((const us*)resid)[(size_t)r * DM + hdx])
                         : ((const float*)resid)[(size_t)r * DM + hdx];
        float x = a[(size_t)r * DM + hdx] + rv;
        xs[hdx] = x;
        lsum += x;
    }
    float m = block_reduce<false>(lsum, red, t) * (1.0f / DM);
    float lv = 0.f;
    #pragma unroll
    for (int u = 0; u < 4; ++u) {
        int hdx = t + 256 * u;
        float dd = xs[hdx] - m;
        lv += dd * dd;
    }
    float var = block_reduce<false>(lv, red, t) * (1.0f / DM);
    float rs = rsqrtf(var + 1e-12f);
    #pragma unroll
    for (int u = 0; u < 4; ++u) {
        int hdx = t + 256 * u;
        float y = (xs[hdx] - m) * rs * g[hdx] + bb[hdx];
        if (OUTBF) ((us*)out)[(size_t)r * DM + hdx] = f2bf(y);
        else       ((float*)out)[(size_t)r * DM + hdx] = y;
    }
}

// ---------------- launch -----------------------------------------------------
extern "C" void kernel_launch(void* const* d_in, const int* in_sizes, int n_in,
                              void* d_out, int out_size, void* d_ws, size_t ws_size,
                              hipStream_t stream) {
    const float* h         = (const float*)d_in[0];
    const float* mems      = (const float*)d_in[1];
    const float* r         = (const float*)d_in[2];
    const float* seg_mat   = (const float*)d_in[3];
    const float* wq        = (const float*)d_in[5];
    const float* wk        = (const float*)d_in[6];
    const float* wv        = (const float*)d_in[7];
    const float* wo        = (const float*)d_in[8];
    const float* wr        = (const float*)d_in[9];
    const float* rwb       = (const float*)d_in[10];
    const float* rrb       = (const float*)d_in[11];
    const float* rsb       = (const float*)d_in[12];
    const float* seg_embed = (const float*)d_in[13];
    const float* ln_g      = (const float*)d_in[14];
    const float* ln_b      = (const float*)d_in[15];
    const float* w1        = (const float*)d_in[16];
    const float* b1        = (const float*)d_in[17];
    const float* w2        = (const float*)d_in[18];
    const float* b2        = (const float*)d_in[19];
    const float* lf_g      = (const float*)d_in[20];
    const float* lf_b      = (const float*)d_in[21];
    float* out = (float*)d_out;
    char* W = (char*)d_ws;
    const size_t MB = 1ull << 20;

    // ws layout (MiB offsets), high-water 87 MiB (<= 88 proven in round 1)
    us*    cat_bf = (us*)(W);                 // 8  [4096][1024]: mems rows 0..2047, h rows 2048..4095
    us*    h_bf   = cat_bf + 2048 * 1024;
    us*    r_bf   = (us*)(W + 8  * MB);       // 12 [6144][1024]
    us*    wq_t   = (us*)(W + 20 * MB);       // 2  [1024][1024]
    us*    wk_t   = (us*)(W + 22 * MB);
    us*    wv_t   = (us*)(W + 24 * MB);
    us*    wr_t   = (us*)(W + 26 * MB);
    us*    wo_b   = (us*)(W + 28 * MB);       // 2  wo as-is ([h][nd] == Bt)
    us*    w1_t   = (us*)(W + 30 * MB);       // 8  [4096][1024]
    us*    w2_t   = (us*)(W + 38 * MB);       // 8  [1024][4096]
    us*    q_bf   = (us*)(W + 46 * MB);       // 4  [32][1024][64]
    us*    k_bf   = (us*)(W + 50 * MB);       // 8  [32][2048][64]
    us*    v_bf   = (us*)(W + 58 * MB);       // 8
    us*    kr_bf  = (us*)(W + 66 * MB);       // 12 [32][3072][64]
    us*    av_bf  = (us*)(W + 78 * MB);       // 4  [2048][1024]
    float* Qx     = (float*)(W + 82 * MB);    // 256 KB
    us*    ks_bf  = (us*)(W + 82 * MB + 512 * 1024);  // 8 KB
    us*    oh_bf  = (us*)(W + 83 * MB);       // 4  [2048][1024]
    float* ao     = (float*)(W + 8 * MB);     // 8  overlay r_bf (dead after kr proj)
    us*    ff1_bf = (us*)(W + 46 * MB);       // 16 overlay q/k/v (dead after attn)
    float* ff2    = (float*)(W + 66 * MB);    // 8  overlay kr (dead after attn)

    dim3 blk(256);
    // ---- convert inputs to bf16 ----
    conv_k<<<dim3(1024), blk, 0, stream>>>(mems, cat_bf, 262144);
    conv_k<<<dim3(1024), blk, 0, stream>>>(h,    h_bf,   262144);
    conv_k<<<dim3(3072), blk, 0, stream>>>(r,    r_bf,   786432);
    conv_k<<<dim3(512),  blk, 0, stream>>>(wo,   wo_b,   131072);
    // ---- transpose-convert weights to Bt[N][K] bf16 ----
    tconv_k<<<dim3(16, 16), blk, 0, stream>>>(wq, wq_t, 1024, 1024);
    tconv_k<<<dim3(16, 16), blk, 0, stream>>>(wk, wk_t, 1024, 1024);
    tconv_k<<<dim3(16, 16), blk, 0, stream>>>(wv, wv_t, 1024, 1024);
    tconv_k<<<dim3(16, 16), blk, 0, stream>>>(wr, wr_t, 1024, 1024);
    tconv_k<<<dim3(64, 16), blk, 0, stream>>>(w1, w1_t, 1024, 4096);
    tconv_k<<<dim3(16, 64), blk, 0, stream>>>(w2, w2_t, 4096, 1024);
    // ---- projections (bf16 MFMA, scatter to [bn][seq][64]) ----
    gemm_mfma<3><<<dim3(8, 16), blk, 0, stream>>>(h_bf,   wq_t, nullptr, q_bf,  2048, 1024, 1024);
    gemm_mfma<3><<<dim3(8, 32), blk, 0, stream>>>(cat_bf, wk_t, nullptr, k_bf,  4096, 1024, 1024);
    gemm_mfma<3><<<dim3(8, 32), blk, 0, stream>>>(cat_bf, wv_t, nullptr, v_bf,  4096, 1024, 1024);
    gemm_mfma<3><<<dim3(8, 48), blk, 0, stream>>>(r_bf,   wr_t, nullptr, kr_bf, 6144, 1024, 1024);
    // ---- seg features + attention ----
    ks_k<<<dim3(16), blk, 0, stream>>>(seg_mat, ks_bf);
    eqx_k<<<dim3(8192), blk, 0, stream>>>(q_bf, rsb, seg_embed, seg_mat, Qx);
    attn2_k<<<dim3(16, 32), blk, 0, stream>>>(q_bf, k_bf, v_bf, kr_bf, ks_bf, Qx, rwb, rrb, av_bf);
    // ---- output proj + LN1 ----
    gemm_mfma<0><<<dim3(8, 16), blk, 0, stream>>>(av_bf, wo_b, nullptr, ao, 2048, 1024, 1024);
    ln_k<false, true><<<dim3(2048), blk, 0, stream>>>(ao, h, ln_g, ln_b, oh_bf);
    // ---- FFN ----
    gemm_mfma<1><<<dim3(32, 16), blk, 0, stream>>>(oh_bf,  w1_t, b1, ff1_bf, 2048, 4096, 1024);
    gemm_mfma<2><<<dim3(8, 16),  blk, 0, stream>>>(ff1_bf, w2_t, b2, ff2,    2048, 1024, 4096);
    // ---- final LN -> d_out ----
    ln_k<true, false><<<dim3(2048), blk, 0, stream>>>(ff2, oh_bf, lf_g, lf_b, out);
}

// Round 4
// 375.120 us; speedup vs baseline: 15.8773x; 1.3711x over previous
//
#include <hip/hip_runtime.h>
#include <hip/hip_bf16.h>

// XLNet rel-attn layer + FFN. Round 4: pipelined MFMA GEMMs (2-phase counted
// vmcnt), merged q/k/v projection, split-K for narrow GEMMs, XCD swizzle.
// QLEN=1024 MLEN=1024 BSZ=2 DM=1024 NH=16 DH=64 DI=4096 KLEN=2048 RLEN=3072.

#define QLEN 1024
#define MLEN 1024
#define DM 1024
#define NH 16
#define DH 64
#define DI 4096
#define KLEN 2048
#define RLEN 3072

typedef __attribute__((ext_vector_type(8))) short s16x8;
typedef __attribute__((ext_vector_type(4))) float f32x4;
typedef unsigned short us;

__device__ __forceinline__ float bf2f(us u) {
    union { unsigned int i; float f; } x; x.i = ((unsigned int)u) << 16; return x.f;
}
__device__ __forceinline__ us f2bf(float f) {
    union { float f; unsigned int i; } x; x.f = f;
    return (us)((x.i + 0x7fffu + ((x.i >> 16) & 1u)) >> 16);
}
__device__ __forceinline__ void gload16(const void* g, void* lds) {
    __builtin_amdgcn_global_load_lds(
        (const __attribute__((address_space(1))) unsigned int*)g,
        (__attribute__((address_space(3))) unsigned int*)lds, 16, 0, 0);
}

// ---------------- block reduction (wave=64, 4 waves/block) ------------------
template<bool ISMAX>
__device__ __forceinline__ float block_reduce(float v, float* red, int t) {
    #pragma unroll
    for (int off = 32; off > 0; off >>= 1) {
        float o = __shfl_down(v, off);
        v = ISMAX ? fmaxf(v, o) : (v + o);
    }
    if ((t & 63) == 0) red[t >> 6] = v;
    __syncthreads();
    if (t == 0) {
        float s = red[0];
        #pragma unroll
        for (int w = 1; w < 4; ++w) s = ISMAX ? fmaxf(s, red[w]) : (s + red[w]);
        red[4] = s;
    }
    __syncthreads();
    return red[4];
}

// ---------------- fp32 -> bf16 convert --------------------------------------
__global__ __launch_bounds__(256) void conv_k(const float* __restrict__ in,
                                              us* __restrict__ out, int n8) {
    int t = blockIdx.x * 256 + threadIdx.x;
    if (t >= n8) return;
    const float4* p = (const float4*)in + 2 * (size_t)t;
    float4 a = p[0], b = p[1];
    us o[8] = { f2bf(a.x), f2bf(a.y), f2bf(a.z), f2bf(a.w),
                f2bf(b.x), f2bf(b.y), f2bf(b.z), f2bf(b.w) };
    *((uint4*)out + t) = *(const uint4*)o;
}

// ---------------- fp32 -> bf16 transpose-convert: out[C][R] = in[R][C]^T ----
__global__ __launch_bounds__(256) void tconv_k(const float* __restrict__ in,
                                               us* __restrict__ out, int R, int C) {
    __shared__ us t[64][65];
    const int tid = threadIdx.x;
    const int c0 = blockIdx.x * 64, r0 = blockIdx.y * 64;
    #pragma unroll
    for (int u = 0; u < 16; ++u) {
        int idx = tid + 256 * u;
        int rr = idx >> 6, cc = idx & 63;
        t[cc][rr] = f2bf(in[(size_t)(r0 + rr) * C + c0 + cc]);
    }
    __syncthreads();
    #pragma unroll
    for (int u = 0; u < 16; ++u) {
        int idx = tid + 256 * u;
        int rr = idx >> 6, cc = idx & 63;
        out[(size_t)(c0 + rr) * R + r0 + cc] = t[rr][cc];
    }
}

// ---------------- pipelined bf16 MFMA GEMM ----------------------------------
// C[M,N] = A[M,K] @ Bt[N,K]^T. Tile TM x 128, BK=32, 4 waves, double-buffered
// LDS, counted vmcnt + raw s_barrier, XCD swizzle, split-K via blockIdx.z.
// EPI: 0 f32; 1 bias+gelu->bf16; 2 bias(z0)->f32; 3 bf16 scatter [bn][seq][64];
//      4 merged qkv scatter.
template<int TM, int EPI>
__global__ __launch_bounds__(256) void gemm2(
    const us* __restrict__ A, const us* __restrict__ Bt,
    const float* __restrict__ bias, void* __restrict__ Cout,
    int M, int N, int K, int kchunk, size_t zstride)
{
    constexpr int MF = TM / 32;
    constexpr int AISS = TM / 64;
    __shared__ us As[2][TM * 32];
    __shared__ us Bs[2][128 * 32];

    const int tid = threadIdx.x;
    const int w = tid >> 6, l = tid & 63;
    const int lm = l & 15, lg = l >> 4;

    int lin = blockIdx.y * gridDim.x + blockIdx.x;
    int nwg = gridDim.x * gridDim.y;
    int swz = (lin & 7) * (nwg >> 3) + (lin >> 3);
    int bx = swz % gridDim.x, by = swz / gridDim.x;
    const int m0 = by * TM, n0 = bx * 128;
    const int wr = (w >> 1) * (TM / 2), wc = (w & 1) * 64;
    const int kbeg = blockIdx.z * kchunk;
    const int nt = kchunk / 32;

    f32x4 acc[MF][4] = {};

    auto stage = [&](int buf, int k0) {
        #pragma unroll
        for (int u = 0; u < AISS; ++u) {
            int c = (u * 4 + w) * 64 + l;
            int row = c & (TM - 1), kc = c >> (TM == 128 ? 7 : 6);
            gload16(A + (size_t)(m0 + row) * K + k0 + kc * 8,
                    &As[buf][(u * 4 + w) * 512]);
        }
        #pragma unroll
        for (int u = 0; u < 2; ++u) {
            int c = (u * 4 + w) * 64 + l;
            int row = c & 127, kc = c >> 7;
            gload16(Bt + (size_t)(n0 + row) * K + k0 + kc * 8,
                    &Bs[buf][(u * 4 + w) * 512]);
        }
    };

    stage(0, kbeg);
    int cur = 0;
    for (int t = 0; t < nt; ++t) {
        if (t + 1 < nt) {
            stage(cur ^ 1, kbeg + (t + 1) * 32);
            if constexpr (TM == 128) asm volatile("s_waitcnt vmcnt(4)" ::: "memory");
            else                     asm volatile("s_waitcnt vmcnt(3)" ::: "memory");
        } else {
            asm volatile("s_waitcnt vmcnt(0)" ::: "memory");
        }
        __builtin_amdgcn_s_barrier();

        s16x8 af[MF], bfr[4];
        #pragma unroll
        for (int mf = 0; mf < MF; ++mf)
            af[mf] = *(const s16x8*)&As[cur][(lg * TM + wr + mf * 16 + lm) * 8];
        #pragma unroll
        for (int nf = 0; nf < 4; ++nf)
            bfr[nf] = *(const s16x8*)&Bs[cur][(lg * 128 + wc + nf * 16 + lm) * 8];
        #pragma unroll
        for (int mf = 0; mf < MF; ++mf)
            #pragma unroll
            for (int nf = 0; nf < 4; ++nf)
                acc[mf][nf] = __builtin_amdgcn_mfma_f32_16x16x32_bf16(
                    af[mf], bfr[nf], acc[mf][nf], 0, 0, 0);

        __builtin_amdgcn_s_barrier();
        cur ^= 1;
    }

    float* Cf = (float*)Cout + (size_t)blockIdx.z * zstride;
    #pragma unroll
    for (int mf = 0; mf < MF; ++mf) {
        #pragma unroll
        for (int nf = 0; nf < 4; ++nf) {
            #pragma unroll
            for (int rr = 0; rr < 4; ++rr) {
                int row = m0 + wr + mf * 16 + lg * 4 + rr;
                int col = n0 + wc + nf * 16 + lm;
                float v = acc[mf][nf][rr];
                if (EPI == 1 || (EPI == 2 && blockIdx.z == 0)) v += bias[col];
                if (EPI == 1) {
                    float targ = 0.7978845608028654f * (v + 0.044715f * v * v * v);
                    v = 0.5f * v * (1.0f + tanhf(targ));
                }
                if (EPI == 0 || EPI == 2) {
                    Cf[(size_t)row * N + col] = v;
                } else if (EPI == 1) {
                    ((us*)Cout)[(size_t)row * N + col] = f2bf(v);
                } else if (EPI == 3) {
                    int nn = col >> 6, dd = col & 63, bb = row & 1;
                    ((us*)Cout)[(((size_t)(bb * 16 + nn)) * (size_t)(M >> 1) + (row >> 1)) * 64 + dd] = f2bf(v);
                } else {
                    int which = col >> 10;
                    int nn = (col >> 6) & 15, dd = col & 63, bb = row & 1;
                    us val = f2bf(v);
                    us* qb = (us*)Cout;
                    if (which == 0) {
                        if (row >= 2048)
                            qb[(((size_t)(bb * 16 + nn)) * 1024 + ((row - 2048) >> 1)) * 64 + dd] = val;
                    } else {
                        us* base = qb + (which == 1 ? 2097152 : 6291456);
                        base[(((size_t)(bb * 16 + nn)) * 2048 + (row >> 1)) * 64 + dd] = val;
                    }
                }
            }
        }
    }
}

// ---------------- ks extraction: ks[b][j] = seg_mat[0,j,b,1] ----------------
__global__ __launch_bounds__(256) void ks_k(const float* __restrict__ seg, us* __restrict__ ksb) {
    int t = blockIdx.x * 256 + threadIdx.x;
    int b = t >> 11, j = t & 2047;
    ksb[t] = f2bf(seg[(size_t)j * 4 + b * 2 + 1]);
}

// ---------------- Qx features ------------------------------------------------
__global__ __launch_bounds__(256) void eqx_k(
    const us* __restrict__ qb, const float* __restrict__ rsb,
    const float* __restrict__ se, const float* __restrict__ seg,
    float* __restrict__ Qx)
{
    int task = blockIdx.x * 4 + (threadIdx.x >> 6);
    int l = threadIdx.x & 63;
    int bn = task >> 10, i = task & 1023;
    int b = bn >> 4, n = bn & 15;
    float q = bf2f(qb[((size_t)bn * QLEN + i) * DH + l]) + rsb[n * DH + l];
    float e0 = q * se[(0 * NH + n) * DH + l];
    float e1 = q * se[(1 * NH + n) * DH + l];
    #pragma unroll
    for (int off = 32; off > 0; off >>= 1) {
        e0 += __shfl_xor(e0, off);
        e1 += __shfl_xor(e1, off);
    }
    if (l == 0) {
        float qsI = seg[(size_t)i * 8192 + b * 2 + 1];
        float qs0 = seg[b * 2 + 1];
        float qs = (qsI != qs0) ? 1.f : 0.f;
        float ed = e1 - e0;
        Qx[((size_t)bn * QLEN + i) * 2 + 0] = e0 + qs * ed;
        Qx[((size_t)bn * QLEN + i) * 2 + 1] = ed * (1.f - 2.f * qs);
    }
}

// ---------------- MFMA flash attention --------------------------------------
__global__ __launch_bounds__(256) void attn2_k(
    const us* __restrict__ qb, const us* __restrict__ kb, const us* __restrict__ vb,
    const us* __restrict__ krb, const us* __restrict__ ksb, const float* __restrict__ Qx,
    const float* __restrict__ rwb, const float* __restrict__ rrb,
    us* __restrict__ av)
{
    __shared__ us K_lds[64 * 64];
    __shared__ us KR_lds[128 * 64];
    __shared__ us VT_lds[64 * 64];
    __shared__ float G_lds[4 * 80 * 16];
    __shared__ us P_lds[4 * 16 * 64];

    const int tid = threadIdx.x;
    const int w = tid >> 6, l = tid & 63;
    const int lm = l & 15, lg = l >> 4;
    const int i0 = blockIdx.x * 64;
    const int bn = blockIdx.y;
    const int b = bn >> 4, n = bn & 15;
    const int i = i0 + w * 16 + lm;

    s16x8 qwf[2], qrf[2], qxf;
    {
        const us* qrow = qb + ((size_t)bn * QLEN + i) * DH;
        #pragma unroll
        for (int ks = 0; ks < 2; ++ks) {
            s16x8 v = *(const s16x8*)(qrow + ks * 32 + lg * 8);
            #pragma unroll
            for (int e = 0; e < 8; ++e) {
                int d = ks * 32 + lg * 8 + e;
                float f = bf2f((us)v[e]);
                qwf[ks][e] = (short)f2bf(f + rwb[n * DH + d]);
                qrf[ks][e] = (short)f2bf(f + rrb[n * DH + d]);
            }
        }
        #pragma unroll
        for (int e = 0; e < 8; ++e) qxf[e] = 0;
        if (lg == 0) {
            qxf[0] = (short)f2bf(Qx[((size_t)bn * QLEN + i) * 2 + 0]);
            qxf[1] = (short)f2bf(Qx[((size_t)bn * QLEN + i) * 2 + 1]);
        }
    }

    f32x4 of[4] = {{0,0,0,0},{0,0,0,0},{0,0,0,0},{0,0,0,0}};
    float M = -3.0e38f, L = 0.f;
    float* gw = &G_lds[w * 1280];
    us* pw = &P_lds[w * 1024];

    int njt = ((i0 + 63 + MLEN) >> 6) + 1;
    if (njt > 32) njt = 32;

    for (int jt = 0; jt < njt; ++jt) {
        const int j0 = jt * 64;
        if (jt) __syncthreads();
        #pragma unroll
        for (int u = 0; u < 2; ++u) {
            int c = (w * 2 + u) * 64 + l;
            int row = c >> 3, ch = c & 7;
            gload16(kb + ((size_t)bn * KLEN + j0 + row) * DH + (size_t)((ch ^ (row & 7)) * 8),
                    &K_lds[(w * 2 + u) * 512]);
        }
        const int ur0 = QLEN - i0 - 63 + j0;
        #pragma unroll
        for (int u = 0; u < 4; ++u) {
            int c = (w * 4 + u) * 64 + l;
            int row = c >> 3, ch = c & 7;
            gload16(krb + ((size_t)bn * RLEN + ur0 + row) * DH + (size_t)((ch ^ (row & 7)) * 8),
                    &KR_lds[(w * 4 + u) * 512]);
        }
        #pragma unroll
        for (int u = 0; u < 2; ++u) {
            int j = l;
            int cd = w + u * 4;
            s16x8 vv = *(const s16x8*)(vb + ((size_t)bn * KLEN + j0 + j) * DH + cd * 8);
            #pragma unroll
            for (int e = 0; e < 8; ++e) {
                int d = cd * 8 + e;
                VT_lds[d * 64 + (((j * 2) ^ ((d & 7) << 4)) >> 1)] = (us)vv[e];
            }
        }
        __syncthreads();

        f32x4 sf[4];
        #pragma unroll
        for (int f = 0; f < 4; ++f) {
            f32x4 cfr = {0, 0, 0, 0};
            int row = f * 16 + lm;
            #pragma unroll
            for (int ks = 0; ks < 2; ++ks) {
                s16x8 a = *(const s16x8*)&K_lds[row * 64 + (((ks * 64 + lg * 16) ^ ((row & 7) << 4)) >> 1)];
                cfr = __builtin_amdgcn_mfma_f32_16x16x32_bf16(a, qwf[ks], cfr, 0, 0, 0);
            }
            s16x8 aext;
            #pragma unroll
            for (int e = 0; e < 8; ++e) aext[e] = 0;
            if (lg == 0) {
                aext[0] = (short)0x3F80;
                aext[1] = (short)ksb[b * KLEN + j0 + f * 16 + lm];
            }
            cfr = __builtin_amdgcn_mfma_f32_16x16x32_bf16(aext, qxf, cfr, 0, 0, 0);
            sf[f] = cfr;
        }

        const int woff = 48 - w * 16;
        #pragma unroll
        for (int pf = 0; pf < 5; ++pf) {
            f32x4 g = {0, 0, 0, 0};
            int row = woff + pf * 16 + lm;
            #pragma unroll
            for (int ks = 0; ks < 2; ++ks) {
                s16x8 a = *(const s16x8*)&KR_lds[row * 64 + (((ks * 64 + lg * 16) ^ ((row & 7) << 4)) >> 1)];
                g = __builtin_amdgcn_mfma_f32_16x16x32_bf16(a, qrf[ks], g, 0, 0, 0);
            }
            #pragma unroll
            for (int rr = 0; rr < 4; ++rr)
                gw[(pf * 16 + lg * 4 + rr) * 16 + lm] = g[rr];
        }

        float sv[16];
        float tmax = -3.0e38f;
        #pragma unroll
        for (int f = 0; f < 4; ++f) {
            #pragma unroll
            for (int rr = 0; rr < 4; ++rr) {
                int jl = f * 16 + lg * 4 + rr;
                float bd = gw[(jl + 15 - lm) * 16 + lm];
                float s = (sf[f][rr] + bd) * 0.125f;
                if (j0 + jl > i + MLEN) s = -1.0e30f;
                sv[f * 4 + rr] = s;
                tmax = fmaxf(tmax, s);
            }
        }
        tmax = fmaxf(tmax, __shfl_xor(tmax, 16));
        tmax = fmaxf(tmax, __shfl_xor(tmax, 32));
        float Mnew = fmaxf(M, tmax);
        float scale = __expf(M - Mnew);
        float psum = 0.f;
        unsigned int pk[8];
        #pragma unroll
        for (int f = 0; f < 4; ++f) {
            #pragma unroll
            for (int rp = 0; rp < 2; ++rp) {
                float p0 = __expf(sv[f * 4 + rp * 2] - Mnew);
                float p1 = __expf(sv[f * 4 + rp * 2 + 1] - Mnew);
                psum += p0 + p1;
                pk[f * 2 + rp] = (unsigned int)f2bf(p0) | ((unsigned int)f2bf(p1) << 16);
            }
        }
        psum += __shfl_xor(psum, 16);
        psum += __shfl_xor(psum, 32);
        L = L * scale + psum;
        M = Mnew;
        float rs4[4];
        #pragma unroll
        for (int rr = 0; rr < 4; ++rr)
            rs4[rr] = __shfl(scale, (l & 48) | (lg * 4 + rr));
        #pragma unroll
        for (int df = 0; df < 4; ++df)
            #pragma unroll
            for (int rr = 0; rr < 4; ++rr)
                of[df][rr] *= rs4[rr];
        #pragma unroll
        for (int f = 0; f < 4; ++f) {
            #pragma unroll
            for (int rp = 0; rp < 2; ++rp) {
                int jl2 = f * 16 + lg * 4 + rp * 2;
                *(unsigned int*)&pw[lm * 64 + (((jl2 * 2) ^ ((lm & 7) << 4)) >> 1)] = pk[f * 2 + rp];
            }
        }
        #pragma unroll
        for (int ks = 0; ks < 2; ++ks) {
            s16x8 pa = *(const s16x8*)&pw[lm * 64 + (((ks * 64 + lg * 16) ^ ((lm & 7) << 4)) >> 1)];
            #pragma unroll
            for (int df = 0; df < 4; ++df) {
                int drow = df * 16 + lm;
                s16x8 vB = *(const s16x8*)&VT_lds[drow * 64 + (((ks * 64 + lg * 16) ^ ((lm & 7) << 4)) >> 1)];
                of[df] = __builtin_amdgcn_mfma_f32_16x16x32_bf16(pa, vB, of[df], 0, 0, 0);
            }
        }
    }

    float rl4[4];
    #pragma unroll
    for (int rr = 0; rr < 4; ++rr)
        rl4[rr] = __shfl(L, (l & 48) | (lg * 4 + rr));
    #pragma unroll
    for (int df = 0; df < 4; ++df) {
        #pragma unroll
        for (int rr = 0; rr < 4; ++rr) {
            int m2 = lg * 4 + rr;
            int d = df * 16 + lm;
            int irow = i0 + w * 16 + m2;
            av[((size_t)irow * 2 + b) * DM + n * DH + d] = f2bf(of[df][rr] / rl4[rr]);
        }
    }
}

// ---------------- residual + layer-norm (optional 2-partial sum) ------------
template<bool SUM2, bool RESBF, bool OUTBF>
__global__ __launch_bounds__(256) void ln_k(
    const float* __restrict__ a, const float* __restrict__ a2,
    const void* __restrict__ resid,
    const float* __restrict__ g, const float* __restrict__ bb,
    void* __restrict__ out)
{
    __shared__ float xs[DM];
    __shared__ float red[5];
    const int r = blockIdx.x;
    const int t = threadIdx.x;
    float lsum = 0.f;
    #pragma unroll
    for (int u = 0; u < 4; ++u) {
        int hdx = t + 256 * u;
        float rv = RESBF ? bf2f(((const us*)resid)[(size_t)r * DM + hdx])
                         : ((const float*)resid)[(size_t)r * DM + hdx];
        float x = a[(size_t)r * DM + hdx] + rv;
        if (SUM2) x += a2[(size_t)r * DM + hdx];
        xs[hdx] = x;
        lsum += x;
    }
    float m = block_reduce<false>(lsum, red, t) * (1.0f / DM);
    float lv = 0.f;
    #pragma unroll
    for (int u = 0; u < 4; ++u) {
        int hdx = t + 256 * u;
        float dd = xs[hdx] - m;
        lv += dd * dd;
    }
    float var = block_reduce<false>(lv, red, t) * (1.0f / DM);
    float rs = rsqrtf(var + 1e-12f);
    #pragma unroll
    for (int u = 0; u < 4; ++u) {
        int hdx = t + 256 * u;
        float y = (xs[hdx] - m) * rs * g[hdx] + bb[hdx];
        if (OUTBF) ((us*)out)[(size_t)r * DM + hdx] = f2bf(y);
        else       ((float*)out)[(size_t)r * DM + hdx] = y;
    }
}

// ---------------- launch -----------------------------------------------------
extern "C" void kernel_launch(void* const* d_in, const int* in_sizes, int n_in,
                              void* d_out, int out_size, void* d_ws, size_t ws_size,
                              hipStream_t stream) {
    const float* h         = (const float*)d_in[0];
    const float* mems      = (const float*)d_in[1];
    const float* r         = (const float*)d_in[2];
    const float* seg_mat   = (const float*)d_in[3];
    const float* wq        = (const float*)d_in[5];
    const float* wk        = (const float*)d_in[6];
    const float* wv        = (const float*)d_in[7];
    const float* wo        = (const float*)d_in[8];
    const float* wr        = (const float*)d_in[9];
    const float* rwb       = (const float*)d_in[10];
    const float* rrb       = (const float*)d_in[11];
    const float* rsb       = (const float*)d_in[12];
    const float* seg_embed = (const float*)d_in[13];
    const float* ln_g      = (const float*)d_in[14];
    const float* ln_b      = (const float*)d_in[15];
    const float* w1        = (const float*)d_in[16];
    const float* b1        = (const float*)d_in[17];
    const float* w2        = (const float*)d_in[18];
    const float* b2        = (const float*)d_in[19];
    const float* lf_g      = (const float*)d_in[20];
    const float* lf_b      = (const float*)d_in[21];
    float* out = (float*)d_out;
    char* W = (char*)d_ws;
    const size_t MB = 1ull << 20;

    us*    cat_bf = (us*)(W);
    us*    r_bf   = (us*)(W + 8  * MB);
    us*    wqkv_t = (us*)(W + 20 * MB);
    us*    wr_t   = (us*)(W + 26 * MB);
    us*    wo_b   = (us*)(W + 28 * MB);
    us*    w1_t   = (us*)(W + 30 * MB);
    us*    w2_t   = (us*)(W + 38 * MB);
    us*    q_bf   = (us*)(W + 46 * MB);
    us*    kr_bf  = (us*)(W + 66 * MB);
    us*    av_bf  = (us*)(W + 78 * MB);
    float* Qx     = (float*)(W + 82 * MB);
    us*    ks_bf  = (us*)(W + 82 * MB + 512 * 1024);
    us*    oh_bf  = (us*)(W + 83 * MB);
    float* ao     = (float*)(W + 8 * MB);
    us*    ff1_bf = (us*)(W + 46 * MB);
    float* ff2    = (float*)(W + 62 * MB);
    us*    k_bf   = q_bf + 2097152;
    us*    v_bf   = q_bf + 6291456;

    dim3 blk(256);
    conv_k<<<dim3(1024), blk, 0, stream>>>(mems, cat_bf, 262144);
    conv_k<<<dim3(1024), blk, 0, stream>>>(h,    cat_bf + 2048 * 1024, 262144);
    conv_k<<<dim3(3072), blk, 0, stream>>>(r,    r_bf,   786432);
    conv_k<<<dim3(512),  blk, 0, stream>>>(wo,   wo_b,   131072);
    tconv_k<<<dim3(16, 16), blk, 0, stream>>>(wq, wqkv_t,               1024, 1024);
    tconv_k<<<dim3(16, 16), blk, 0, stream>>>(wk, wqkv_t + 1024 * 1024, 1024, 1024);
    tconv_k<<<dim3(16, 16), blk, 0, stream>>>(wv, wqkv_t + 2048 * 1024, 1024, 1024);
    tconv_k<<<dim3(16, 16), blk, 0, stream>>>(wr, wr_t, 1024, 1024);
    tconv_k<<<dim3(64, 16), blk, 0, stream>>>(w1, w1_t, 1024, 4096);
    tconv_k<<<dim3(16, 64), blk, 0, stream>>>(w2, w2_t, 4096, 1024);
    gemm2<128, 4><<<dim3(24, 32), blk, 0, stream>>>(cat_bf, wqkv_t, nullptr, q_bf, 4096, 3072, 1024, 1024, 0);
    gemm2<64, 3><<<dim3(8, 96), blk, 0, stream>>>(r_bf, wr_t, nullptr, kr_bf, 6144, 1024, 1024, 1024, 0);
    ks_k<<<dim3(16), blk, 0, stream>>>(seg_mat, ks_bf);
    eqx_k<<<dim3(8192), blk, 0, stream>>>(q_bf, rsb, seg_embed, seg_mat, Qx);
    attn2_k<<<dim3(16, 32), blk, 0, stream>>>(q_bf, k_bf, v_bf, kr_bf, ks_bf, Qx, rwb, rrb, av_bf);
    gemm2<64, 0><<<dim3(8, 32, 2), blk, 0, stream>>>(av_bf, wo_b, nullptr, ao, 2048, 1024, 1024, 512, 2097152);
    ln_k<true, false, true><<<dim3(2048), blk, 0, stream>>>(ao, ao + 2097152, h, ln_g, ln_b, oh_bf);
    gemm2<128, 1><<<dim3(32, 16), blk, 0, stream>>>(oh_bf, w1_t, b1, ff1_bf, 2048, 4096, 1024, 1024, 0);
    gemm2<64, 2><<<dim3(8, 32, 2), blk, 0, stream>>>(ff1_bf, w2_t, b2, ff2, 2048, 1024, 4096, 2048, 2097152);
    ln_k<true, true, false><<<dim3(2048), blk, 0, stream>>>(ff2, ff2 + 2097152, oh_bf, lf_g, lf_b, out);
}

// Round 5
// 346.839 us; speedup vs baseline: 17.1719x; 1.0815x over previous
//
#include <hip/hip_runtime.h>
#include <hip/hip_bf16.h>

// XLNet rel-attn layer + FFN. Round 5: pipelined flash attention (dbuf K,
// early-issue V, post-barrier KR prefetch), conflict-free G (stride 20),
// exp2-domain softmax + cvt_pk packing, merged conversion launches.
// QLEN=1024 MLEN=1024 BSZ=2 DM=1024 NH=16 DH=64 DI=4096 KLEN=2048 RLEN=3072.

#define QLEN 1024
#define MLEN 1024
#define DM 1024
#define NH 16
#define DH 64
#define DI 4096
#define KLEN 2048
#define RLEN 3072

typedef __attribute__((ext_vector_type(8))) short s16x8;
typedef __attribute__((ext_vector_type(4))) float f32x4;
typedef unsigned short us;

__device__ __forceinline__ float bf2f(us u) {
    union { unsigned int i; float f; } x; x.i = ((unsigned int)u) << 16; return x.f;
}
__device__ __forceinline__ us f2bf(float f) {
    union { float f; unsigned int i; } x; x.f = f;
    return (us)((x.i + 0x7fffu + ((x.i >> 16) & 1u)) >> 16);
}
__device__ __forceinline__ void gload16(const void* g, void* lds) {
    __builtin_amdgcn_global_load_lds(
        (const __attribute__((address_space(1))) unsigned int*)g,
        (__attribute__((address_space(3))) unsigned int*)lds, 16, 0, 0);
}

// ---------------- block reduction (wave=64, 4 waves/block) ------------------
template<bool ISMAX>
__device__ __forceinline__ float block_reduce(float v, float* red, int t) {
    #pragma unroll
    for (int off = 32; off > 0; off >>= 1) {
        float o = __shfl_down(v, off);
        v = ISMAX ? fmaxf(v, o) : (v + o);
    }
    if ((t & 63) == 0) red[t >> 6] = v;
    __syncthreads();
    if (t == 0) {
        float s = red[0];
        #pragma unroll
        for (int w = 1; w < 4; ++w) s = ISMAX ? fmaxf(s, red[w]) : (s + red[w]);
        red[4] = s;
    }
    __syncthreads();
    return red[4];
}

// ---------------- fused fp32 -> bf16 convert (mems,h,r,wo in one launch) ----
__global__ __launch_bounds__(256) void convall_k(
    const float* __restrict__ mems, const float* __restrict__ h,
    const float* __restrict__ r, const float* __restrict__ wo,
    us* __restrict__ cat_bf, us* __restrict__ r_bf, us* __restrict__ wo_b)
{
    int t = blockIdx.x * 256 + threadIdx.x;   // 1441792 units of 8 floats
    const float* src; us* dst; int off;
    if (t < 262144)       { src = mems; dst = cat_bf;           off = t; }
    else if (t < 524288)  { src = h;    dst = cat_bf + 2097152; off = t - 262144; }
    else if (t < 1310720) { src = r;    dst = r_bf;             off = t - 524288; }
    else                  { src = wo;   dst = wo_b;             off = t - 1310720; }
    const float4* p = (const float4*)src + 2 * (size_t)off;
    float4 a = p[0], b = p[1];
    us o[8] = { f2bf(a.x), f2bf(a.y), f2bf(a.z), f2bf(a.w),
                f2bf(b.x), f2bf(b.y), f2bf(b.z), f2bf(b.w) };
    *((uint4*)dst + off) = *(const uint4*)o;
}

// ---------------- fp32 -> bf16 transpose-convert: out[C][R] = in[R][C]^T ----
__global__ __launch_bounds__(256) void tconv_k(const float* __restrict__ in,
                                               us* __restrict__ out, int R, int C) {
    __shared__ us t[64][65];
    const int tid = threadIdx.x;
    const int c0 = blockIdx.x * 64, r0 = blockIdx.y * 64;
    #pragma unroll
    for (int u = 0; u < 16; ++u) {
        int idx = tid + 256 * u;
        int rr = idx >> 6, cc = idx & 63;
        t[cc][rr] = f2bf(in[(size_t)(r0 + rr) * C + c0 + cc]);
    }
    __syncthreads();
    #pragma unroll
    for (int u = 0; u < 16; ++u) {
        int idx = tid + 256 * u;
        int rr = idx >> 6, cc = idx & 63;
        out[(size_t)(c0 + rr) * R + r0 + cc] = t[rr][cc];
    }
}

// ---------------- 4x 1024^2 transpose-converts in one launch ----------------
__global__ __launch_bounds__(256) void tconv4_k(
    const float* __restrict__ wq, const float* __restrict__ wk,
    const float* __restrict__ wv, const float* __restrict__ wr,
    us* __restrict__ wqkv_t, us* __restrict__ wr_t)
{
    __shared__ us t[64][65];
    const int z = blockIdx.z;
    const float* in = (z == 0) ? wq : (z == 1) ? wk : (z == 2) ? wv : wr;
    us* out = (z < 3) ? (wqkv_t + (size_t)z * 1048576) : wr_t;
    const int tid = threadIdx.x;
    const int c0 = blockIdx.x * 64, r0 = blockIdx.y * 64;
    #pragma unroll
    for (int u = 0; u < 16; ++u) {
        int idx = tid + 256 * u;
        int rr = idx >> 6, cc = idx & 63;
        t[cc][rr] = f2bf(in[(size_t)(r0 + rr) * 1024 + c0 + cc]);
    }
    __syncthreads();
    #pragma unroll
    for (int u = 0; u < 16; ++u) {
        int idx = tid + 256 * u;
        int rr = idx >> 6, cc = idx & 63;
        out[(size_t)(c0 + rr) * 1024 + r0 + cc] = t[rr][cc];
    }
}

// ---------------- pipelined bf16 MFMA GEMM (unchanged from round 4) ---------
template<int TM, int EPI>
__global__ __launch_bounds__(256) void gemm2(
    const us* __restrict__ A, const us* __restrict__ Bt,
    const float* __restrict__ bias, void* __restrict__ Cout,
    int M, int N, int K, int kchunk, size_t zstride)
{
    constexpr int MF = TM / 32;
    constexpr int AISS = TM / 64;
    __shared__ us As[2][TM * 32];
    __shared__ us Bs[2][128 * 32];

    const int tid = threadIdx.x;
    const int w = tid >> 6, l = tid & 63;
    const int lm = l & 15, lg = l >> 4;

    int lin = blockIdx.y * gridDim.x + blockIdx.x;
    int nwg = gridDim.x * gridDim.y;
    int swz = (lin & 7) * (nwg >> 3) + (lin >> 3);
    int bx = swz % gridDim.x, by = swz / gridDim.x;
    const int m0 = by * TM, n0 = bx * 128;
    const int wr = (w >> 1) * (TM / 2), wc = (w & 1) * 64;
    const int kbeg = blockIdx.z * kchunk;
    const int nt = kchunk / 32;

    f32x4 acc[MF][4] = {};

    auto stage = [&](int buf, int k0) {
        #pragma unroll
        for (int u = 0; u < AISS; ++u) {
            int c = (u * 4 + w) * 64 + l;
            int row = c & (TM - 1), kc = c >> (TM == 128 ? 7 : 6);
            gload16(A + (size_t)(m0 + row) * K + k0 + kc * 8,
                    &As[buf][(u * 4 + w) * 512]);
        }
        #pragma unroll
        for (int u = 0; u < 2; ++u) {
            int c = (u * 4 + w) * 64 + l;
            int row = c & 127, kc = c >> 7;
            gload16(Bt + (size_t)(n0 + row) * K + k0 + kc * 8,
                    &Bs[buf][(u * 4 + w) * 512]);
        }
    };

    stage(0, kbeg);
    int cur = 0;
    for (int t = 0; t < nt; ++t) {
        if (t + 1 < nt) {
            stage(cur ^ 1, kbeg + (t + 1) * 32);
            if constexpr (TM == 128) asm volatile("s_waitcnt vmcnt(4)" ::: "memory");
            else                     asm volatile("s_waitcnt vmcnt(3)" ::: "memory");
        } else {
            asm volatile("s_waitcnt vmcnt(0)" ::: "memory");
        }
        __builtin_amdgcn_s_barrier();

        s16x8 af[MF], bfr[4];
        #pragma unroll
        for (int mf = 0; mf < MF; ++mf)
            af[mf] = *(const s16x8*)&As[cur][(lg * TM + wr + mf * 16 + lm) * 8];
        #pragma unroll
        for (int nf = 0; nf < 4; ++nf)
            bfr[nf] = *(const s16x8*)&Bs[cur][(lg * 128 + wc + nf * 16 + lm) * 8];
        #pragma unroll
        for (int mf = 0; mf < MF; ++mf)
            #pragma unroll
            for (int nf = 0; nf < 4; ++nf)
                acc[mf][nf] = __builtin_amdgcn_mfma_f32_16x16x32_bf16(
                    af[mf], bfr[nf], acc[mf][nf], 0, 0, 0);

        __builtin_amdgcn_s_barrier();
        cur ^= 1;
    }

    float* Cf = (float*)Cout + (size_t)blockIdx.z * zstride;
    #pragma unroll
    for (int mf = 0; mf < MF; ++mf) {
        #pragma unroll
        for (int nf = 0; nf < 4; ++nf) {
            #pragma unroll
            for (int rr = 0; rr < 4; ++rr) {
                int row = m0 + wr + mf * 16 + lg * 4 + rr;
                int col = n0 + wc + nf * 16 + lm;
                float v = acc[mf][nf][rr];
                if (EPI == 1 || (EPI == 2 && blockIdx.z == 0)) v += bias[col];
                if (EPI == 1) {
                    float targ = 0.7978845608028654f * (v + 0.044715f * v * v * v);
                    v = 0.5f * v * (1.0f + tanhf(targ));
                }
                if (EPI == 0 || EPI == 2) {
                    Cf[(size_t)row * N + col] = v;
                } else if (EPI == 1) {
                    ((us*)Cout)[(size_t)row * N + col] = f2bf(v);
                } else if (EPI == 3) {
                    int nn = col >> 6, dd = col & 63, bb = row & 1;
                    ((us*)Cout)[(((size_t)(bb * 16 + nn)) * (size_t)(M >> 1) + (row >> 1)) * 64 + dd] = f2bf(v);
                } else {
                    int which = col >> 10;
                    int nn = (col >> 6) & 15, dd = col & 63, bb = row & 1;
                    us val = f2bf(v);
                    us* qb = (us*)Cout;
                    if (which == 0) {
                        if (row >= 2048)
                            qb[(((size_t)(bb * 16 + nn)) * 1024 + ((row - 2048) >> 1)) * 64 + dd] = val;
                    } else {
                        us* base = qb + (which == 1 ? 2097152 : 6291456);
                        base[(((size_t)(bb * 16 + nn)) * 2048 + (row >> 1)) * 64 + dd] = val;
                    }
                }
            }
        }
    }
}

// ---------------- Qx features (+ fused ks extraction) -----------------------
__global__ __launch_bounds__(256) void eqx_k(
    const us* __restrict__ qb, const float* __restrict__ rsb,
    const float* __restrict__ se, const float* __restrict__ seg,
    float* __restrict__ Qx, us* __restrict__ ksb)
{
    if (blockIdx.x < 16) {
        int t = blockIdx.x * 256 + threadIdx.x;   // 4096: ks[b][j] = seg[0,j,b,1]
        int bb = t >> 11, j = t & 2047;
        ksb[t] = f2bf(seg[(size_t)j * 4 + bb * 2 + 1]);
    }
    int task = blockIdx.x * 4 + (threadIdx.x >> 6);
    int l = threadIdx.x & 63;
    int bn = task >> 10, i = task & 1023;
    int b = bn >> 4, n = bn & 15;
    float q = bf2f(qb[((size_t)bn * QLEN + i) * DH + l]) + rsb[n * DH + l];
    float e0 = q * se[(0 * NH + n) * DH + l];
    float e1 = q * se[(1 * NH + n) * DH + l];
    #pragma unroll
    for (int off = 32; off > 0; off >>= 1) {
        e0 += __shfl_xor(e0, off);
        e1 += __shfl_xor(e1, off);
    }
    if (l == 0) {
        float qsI = seg[(size_t)i * 8192 + b * 2 + 1];
        float qs0 = seg[b * 2 + 1];
        float qs = (qsI != qs0) ? 1.f : 0.f;
        float ed = e1 - e0;
        Qx[((size_t)bn * QLEN + i) * 2 + 0] = e0 + qs * ed;
        Qx[((size_t)bn * QLEN + i) * 2 + 1] = ed * (1.f - 2.f * qs);
    }
}

// ---------------- pipelined MFMA flash attention ----------------------------
// grid (16 i-tiles, 32 bn), 4 waves. Double-buffered K (gload_lds), V via
// global->reg a tile early, KR single-buffered prefetched after the post-bd
// barrier. G scratch stride 20 (conflict-free). exp2-domain softmax.
__global__ __launch_bounds__(256) void attn3_k(
    const us* __restrict__ qb, const us* __restrict__ kb, const us* __restrict__ vb,
    const us* __restrict__ krb, const us* __restrict__ ksb, const float* __restrict__ Qx,
    const float* __restrict__ rwb, const float* __restrict__ rrb,
    us* __restrict__ av)
{
    __shared__ us K_lds[2][64 * 64];
    __shared__ us KR_lds[128 * 64];
    __shared__ us VT_lds[64 * 64];
    __shared__ float G_lds[4 * 80 * 20];
    __shared__ us P_lds[4 * 16 * 64];
    __shared__ us KS_lds[2048];

    const int tid = threadIdx.x;
    const int w = tid >> 6, l = tid & 63;
    const int lm = l & 15, lg = l >> 4;
    const int i0 = blockIdx.x * 64;
    const int bn = blockIdx.y;
    const int b = bn >> 4, n = bn & 15;
    const int i = i0 + w * 16 + lm;

    const float SC = 0.125f * 1.44269504088896340736f;  // scale * log2(e)

    // hoisted Q fragments, prescaled into exp2 domain
    s16x8 qwf[2], qrf[2], qxf;
    {
        const us* qrow = qb + ((size_t)bn * QLEN + i) * DH;
        #pragma unroll
        for (int ks = 0; ks < 2; ++ks) {
            s16x8 v = *(const s16x8*)(qrow + ks * 32 + lg * 8);
            #pragma unroll
            for (int e = 0; e < 8; ++e) {
                int d = ks * 32 + lg * 8 + e;
                float f = bf2f((us)v[e]);
                qwf[ks][e] = (short)f2bf((f + rwb[n * DH + d]) * SC);
                qrf[ks][e] = (short)f2bf((f + rrb[n * DH + d]) * SC);
            }
        }
        #pragma unroll
        for (int e = 0; e < 8; ++e) qxf[e] = 0;
        if (lg == 0) {
            qxf[0] = (short)f2bf(Qx[((size_t)bn * QLEN + i) * 2 + 0] * SC);
            qxf[1] = (short)f2bf(Qx[((size_t)bn * QLEN + i) * 2 + 1] * SC);
        }
    }

    auto stageK = [&](int buf, int j0) {
        #pragma unroll
        for (int u = 0; u < 2; ++u) {
            int c = (w * 2 + u) * 64 + l;
            int row = c >> 3, ch = c & 7;
            gload16(kb + ((size_t)bn * KLEN + j0 + row) * DH + ((ch ^ (row & 7)) * 8),
                    &K_lds[buf][(w * 2 + u) * 512]);
        }
    };
    auto stageKR = [&](int j0) {
        const int ur0 = QLEN - i0 - 63 + j0;
        #pragma unroll
        for (int u = 0; u < 4; ++u) {
            int c = (w * 4 + u) * 64 + l;
            int row = c >> 3, ch = c & 7;
            gload16(krb + ((size_t)bn * RLEN + ur0 + row) * DH + ((ch ^ (row & 7)) * 8),
                    &KR_lds[(w * 4 + u) * 512]);
        }
    };
    s16x8 vreg[2];
    auto loadV = [&](int j0) {
        #pragma unroll
        for (int u = 0; u < 2; ++u)
            vreg[u] = *(const s16x8*)(vb + ((size_t)bn * KLEN + j0 + l) * DH + (w + u * 4) * 8);
    };

    int njt = ((i0 + 63 + MLEN) >> 6) + 1;
    if (njt > 32) njt = 32;

    // prologue: KS once + tile 0
    gload16(ksb + b * KLEN + (w * 64 + l) * 8, &KS_lds[w * 512]);
    stageK(0, 0);
    stageKR(0);
    loadV(0);

    f32x4 of[4] = {{0,0,0,0},{0,0,0,0},{0,0,0,0},{0,0,0,0}};
    float M = -3.0e38f, L = 0.f;
    float* gw = &G_lds[w * 1600];
    us* pw = &P_lds[w * 1024];
    int cur = 0;

    for (int jt = 0; jt < njt; ++jt) {
        const int j0 = jt * 64;
        asm volatile("s_waitcnt vmcnt(0)" ::: "memory");  // K/KR/V(t) arrived
        __builtin_amdgcn_s_barrier();                     // publish LDS
        asm volatile("" ::: "memory");

        // write VT(t) from vreg; prefetch K(t+1), V(t+1)
        #pragma unroll
        for (int u = 0; u < 2; ++u) {
            #pragma unroll
            for (int e = 0; e < 8; ++e) {
                int d = (w + u * 4) * 8 + e;
                VT_lds[d * 64 + (((l * 2) ^ ((e & 7) << 4)) >> 1)] = (us)vreg[u][e];
            }
        }
        if (jt + 1 < njt) {
            stageK(cur ^ 1, j0 + 64);
            loadV(j0 + 64);
        }

        // ---- ac + ef (K[cur]) and bd (KR) ----
        __builtin_amdgcn_s_setprio(1);
        f32x4 sf[4];
        #pragma unroll
        for (int f = 0; f < 4; ++f) {
            f32x4 cfr = {0, 0, 0, 0};
            int row = f * 16 + lm;
            #pragma unroll
            for (int ks = 0; ks < 2; ++ks) {
                s16x8 a = *(const s16x8*)&K_lds[cur][row * 64 + (((ks * 64 + lg * 16) ^ ((row & 7) << 4)) >> 1)];
                cfr = __builtin_amdgcn_mfma_f32_16x16x32_bf16(a, qwf[ks], cfr, 0, 0, 0);
            }
            s16x8 aext;
            #pragma unroll
            for (int e = 0; e < 8; ++e) aext[e] = 0;
            if (lg == 0) {
                aext[0] = (short)0x3F80;
                aext[1] = (short)KS_lds[j0 + f * 16 + lm];
            }
            cfr = __builtin_amdgcn_mfma_f32_16x16x32_bf16(aext, qxf, cfr, 0, 0, 0);
            sf[f] = cfr;
        }
        const int woff = 48 - w * 16;
        #pragma unroll
        for (int pf = 0; pf < 5; ++pf) {
            f32x4 g = {0, 0, 0, 0};
            int row = woff + pf * 16 + lm;
            #pragma unroll
            for (int ks = 0; ks < 2; ++ks) {
                s16x8 a = *(const s16x8*)&KR_lds[row * 64 + (((ks * 64 + lg * 16) ^ ((row & 7) << 4)) >> 1)];
                g = __builtin_amdgcn_mfma_f32_16x16x32_bf16(a, qrf[ks], g, 0, 0, 0);
            }
            #pragma unroll
            for (int rr = 0; rr < 4; ++rr)
                gw[(pf * 16 + lg * 4 + rr) * 20 + lm] = g[rr];
        }
        __builtin_amdgcn_s_setprio(0);

        // ---- combine + mask + online softmax (exp2 domain) ----
        float sv[16];
        #pragma unroll
        for (int f = 0; f < 4; ++f)
            #pragma unroll
            for (int rr = 0; rr < 4; ++rr) {
                int jl = f * 16 + lg * 4 + rr;
                sv[f * 4 + rr] = sf[f][rr] + gw[(jl + 15 - lm) * 20 + lm];
            }
        if (j0 + 63 > i0 + w * 16 + MLEN) {   // wave-uniform: only boundary tiles
            #pragma unroll
            for (int f = 0; f < 4; ++f)
                #pragma unroll
                for (int rr = 0; rr < 4; ++rr) {
                    int jl = f * 16 + lg * 4 + rr;
                    if (j0 + jl > i + MLEN) sv[f * 4 + rr] = -1.0e30f;
                }
        }
        float tmax = sv[0];
        #pragma unroll
        for (int u = 1; u < 16; ++u) tmax = fmaxf(tmax, sv[u]);
        tmax = fmaxf(tmax, __shfl_xor(tmax, 16));
        tmax = fmaxf(tmax, __shfl_xor(tmax, 32));
        float Mnew = fmaxf(M, tmax);
        float scale;
        asm("v_exp_f32 %0, %1" : "=v"(scale) : "v"(M - Mnew));
        float psum = 0.f;
        unsigned int pk[8];
        #pragma unroll
        for (int f = 0; f < 4; ++f) {
            #pragma unroll
            for (int rp = 0; rp < 2; ++rp) {
                float p0, p1;
                asm("v_exp_f32 %0, %1" : "=v"(p0) : "v"(sv[f * 4 + rp * 2] - Mnew));
                asm("v_exp_f32 %0, %1" : "=v"(p1) : "v"(sv[f * 4 + rp * 2 + 1] - Mnew));
                psum += p0 + p1;
                unsigned int pkv;
                asm("v_cvt_pk_bf16_f32 %0, %1, %2" : "=v"(pkv) : "v"(p0), "v"(p1));
                pk[f * 2 + rp] = pkv;
            }
        }
        psum += __shfl_xor(psum, 16);
        psum += __shfl_xor(psum, 32);
        L = L * scale + psum;
        M = Mnew;
        float rs4[4];
        #pragma unroll
        for (int rr = 0; rr < 4; ++rr)
            rs4[rr] = __shfl(scale, (l & 48) | (lg * 4 + rr));
        #pragma unroll
        for (int df = 0; df < 4; ++df)
            #pragma unroll
            for (int rr = 0; rr < 4; ++rr)
                of[df][rr] *= rs4[rr];
        #pragma unroll
        for (int f = 0; f < 4; ++f) {
            #pragma unroll
            for (int rp = 0; rp < 2; ++rp) {
                int jl2 = f * 16 + lg * 4 + rp * 2;
                *(unsigned int*)&pw[lm * 64 + (((jl2 * 2) ^ ((lm & 7) << 4)) >> 1)] = pk[f * 2 + rp];
            }
        }

        // ---- barrier: VT/P flushed; then prefetch KR(t+1) into freed buffer
        asm volatile("s_waitcnt lgkmcnt(0)" ::: "memory");
        __builtin_amdgcn_s_barrier();
        asm volatile("" ::: "memory");
        if (jt + 1 < njt) stageKR(j0 + 64);

        // ---- PV ----
        __builtin_amdgcn_s_setprio(1);
        #pragma unroll
        for (int ks = 0; ks < 2; ++ks) {
            s16x8 pa = *(const s16x8*)&pw[lm * 64 + (((ks * 64 + lg * 16) ^ ((lm & 7) << 4)) >> 1)];
            #pragma unroll
            for (int df = 0; df < 4; ++df) {
                int drow = df * 16 + lm;
                s16x8 vB = *(const s16x8*)&VT_lds[drow * 64 + (((ks * 64 + lg * 16) ^ ((lm & 7) << 4)) >> 1)];
                of[df] = __builtin_amdgcn_mfma_f32_16x16x32_bf16(pa, vB, of[df], 0, 0, 0);
            }
        }
        __builtin_amdgcn_s_setprio(0);
        cur ^= 1;
    }

    float rl4[4];
    #pragma unroll
    for (int rr = 0; rr < 4; ++rr)
        rl4[rr] = __shfl(L, (l & 48) | (lg * 4 + rr));
    #pragma unroll
    for (int df = 0; df < 4; ++df) {
        #pragma unroll
        for (int rr = 0; rr < 4; ++rr) {
            int m2 = lg * 4 + rr;
            int d = df * 16 + lm;
            int irow = i0 + w * 16 + m2;
            av[((size_t)irow * 2 + b) * DM + n * DH + d] = f2bf(of[df][rr] / rl4[rr]);
        }
    }
}

// ---------------- residual + layer-norm (optional 2-partial sum) ------------
template<bool SUM2, bool RESBF, bool OUTBF>
__global__ __launch_bounds__(256) void ln_k(
    const float* __restrict__ a, const float* __restrict__ a2,
    const void* __restrict__ resid,
    const float* __restrict__ g, const float* __restrict__ bb,
    void* __restrict__ out)
{
    __shared__ float xs[DM];
    __shared__ float red[5];
    const int r = blockIdx.x;
    const int t = threadIdx.x;
    float lsum = 0.f;
    #pragma unroll
    for (int u = 0; u < 4; ++u) {
        int hdx = t + 256 * u;
        float rv = RESBF ? bf2f(((const us*)resid)[(size_t)r * DM + hdx])
                         : ((const float*)resid)[(size_t)r * DM + hdx];
        float x = a[(size_t)r * DM + hdx] + rv;
        if (SUM2) x += a2[(size_t)r * DM + hdx];
        xs[hdx] = x;
        lsum += x;
    }
    float m = block_reduce<false>(lsum, red, t) * (1.0f / DM);
    float lv = 0.f;
    #pragma unroll
    for (int u = 0; u < 4; ++u) {
        int hdx = t + 256 * u;
        float dd = xs[hdx] - m;
        lv += dd * dd;
    }
    float var = block_reduce<false>(lv, red, t) * (1.0f / DM);
    float rs = rsqrtf(var + 1e-12f);
    #pragma unroll
    for (int u = 0; u < 4; ++u) {
        int hdx = t + 256 * u;
        float y = (xs[hdx] - m) * rs * g[hdx] + bb[hdx];
        if (OUTBF) ((us*)out)[(size_t)r * DM + hdx] = f2bf(y);
        else       ((float*)out)[(size_t)r * DM + hdx] = y;
    }
}

// ---------------- launch -----------------------------------------------------
extern "C" void kernel_launch(void* const* d_in, const int* in_sizes, int n_in,
                              void* d_out, int out_size, void* d_ws, size_t ws_size,
                              hipStream_t stream) {
    const float* h         = (const float*)d_in[0];
    const float* mems      = (const float*)d_in[1];
    const float* r         = (const float*)d_in[2];
    const float* seg_mat   = (const float*)d_in[3];
    const float* wq        = (const float*)d_in[5];
    const float* wk        = (const float*)d_in[6];
    const float* wv        = (const float*)d_in[7];
    const float* wo        = (const float*)d_in[8];
    const float* wr        = (const float*)d_in[9];
    const float* rwb       = (const float*)d_in[10];
    const float* rrb       = (const float*)d_in[11];
    const float* rsb       = (const float*)d_in[12];
    const float* seg_embed = (const float*)d_in[13];
    const float* ln_g      = (const float*)d_in[14];
    const float* ln_b      = (const float*)d_in[15];
    const float* w1        = (const float*)d_in[16];
    const float* b1        = (const float*)d_in[17];
    const float* w2        = (const float*)d_in[18];
    const float* b2        = (const float*)d_in[19];
    const float* lf_g      = (const float*)d_in[20];
    const float* lf_b      = (const float*)d_in[21];
    float* out = (float*)d_out;
    char* W = (char*)d_ws;
    const size_t MB = 1ull << 20;

    us*    cat_bf = (us*)(W);
    us*    r_bf   = (us*)(W + 8  * MB);
    us*    wqkv_t = (us*)(W + 20 * MB);
    us*    wr_t   = (us*)(W + 26 * MB);
    us*    wo_b   = (us*)(W + 28 * MB);
    us*    w1_t   = (us*)(W + 30 * MB);
    us*    w2_t   = (us*)(W + 38 * MB);
    us*    q_bf   = (us*)(W + 46 * MB);
    us*    kr_bf  = (us*)(W + 66 * MB);
    us*    av_bf  = (us*)(W + 78 * MB);
    float* Qx     = (float*)(W + 82 * MB);
    us*    ks_bf  = (us*)(W + 82 * MB + 512 * 1024);
    us*    oh_bf  = (us*)(W + 83 * MB);
    float* ao     = (float*)(W + 8 * MB);
    us*    ff1_bf = (us*)(W + 46 * MB);
    float* ff2    = (float*)(W + 62 * MB);
    us*    k_bf   = q_bf + 2097152;
    us*    v_bf   = q_bf + 6291456;

    dim3 blk(256);
    convall_k<<<dim3(5632), blk, 0, stream>>>(mems, h, r, wo, cat_bf, r_bf, wo_b);
    tconv4_k<<<dim3(16, 16, 4), blk, 0, stream>>>(wq, wk, wv, wr, wqkv_t, wr_t);
    tconv_k<<<dim3(64, 16), blk, 0, stream>>>(w1, w1_t, 1024, 4096);
    tconv_k<<<dim3(16, 64), blk, 0, stream>>>(w2, w2_t, 4096, 1024);
    gemm2<128, 4><<<dim3(24, 32), blk, 0, stream>>>(cat_bf, wqkv_t, nullptr, q_bf, 4096, 3072, 1024, 1024, 0);
    gemm2<64, 3><<<dim3(8, 96), blk, 0, stream>>>(r_bf, wr_t, nullptr, kr_bf, 6144, 1024, 1024, 1024, 0);
    eqx_k<<<dim3(8192), blk, 0, stream>>>(q_bf, rsb, seg_embed, seg_mat, Qx, ks_bf);
    attn3_k<<<dim3(16, 32), blk, 0, stream>>>(q_bf, k_bf, v_bf, kr_bf, ks_bf, Qx, rwb, rrb, av_bf);
    gemm2<64, 0><<<dim3(8, 32, 2), blk, 0, stream>>>(av_bf, wo_b, nullptr, ao, 2048, 1024, 1024, 512, 2097152);
    ln_k<true, false, true><<<dim3(2048), blk, 0, stream>>>(ao, ao + 2097152, h, ln_g, ln_b, oh_bf);
    gemm2<128, 1><<<dim3(32, 16), blk, 0, stream>>>(oh_bf, w1_t, b1, ff1_bf, 2048, 4096, 1024, 1024, 0);
    gemm2<64, 2><<<dim3(8, 32, 2), blk, 0, stream>>>(ff1_bf, w2_t, b2, ff2, 2048, 1024, 4096, 2048, 2097152);
    ln_k<true, true, false><<<dim3(2048), blk, 0, stream>>>(ff2, ff2 + 2097152, oh_bf, lf_g, lf_b, out);
}